// Round 4
// baseline (309.632 us; speedup 1.0000x reference)
//
#include <hip/hip_runtime.h>

#define HH 80
#define WW 80
#define BB 8
#define CIN 128
#define C2 256
#define MID 64
#define OFFC 72
#define NG 4
#define CG 32
#define HW (HH * WW)
#define PD 82           // padded spatial dim
#define PP (PD * PD)    // padded pixels per image

typedef short bf16x8 __attribute__((ext_vector_type(8)));
typedef float f32x4  __attribute__((ext_vector_type(4)));

static __device__ __forceinline__ unsigned short f2bf(float f) {
    union { float f; unsigned u; } v; v.f = f;
    unsigned r = v.u + 0x7fffu + ((v.u >> 16) & 1u);   // RNE
    return (unsigned short)(r >> 16);
}

// ---------------- zero the 1-px border of padded bf16 buffers (every call) ----
__global__ __launch_bounds__(256) void zero_borders(
    unsigned short* __restrict__ rgbcp, unsigned short* __restrict__ hdnp)
{
    int idx = blockIdx.x * 256 + threadIdx.x;
    if (idx >= BB * 324) return;
    int b = idx / 324, e = idx - (idx / 324) * 324;
    int y, x;
    if (e < 82)       { y = 0;  x = e; }
    else if (e < 164) { y = 81; x = e - 82; }
    else if (e < 244) { y = e - 164 + 1; x = 0; }
    else              { y = e - 244 + 1; x = 81; }
    size_t pos = (size_t)b * PP + y * PD + x;
    uint4 z = {0, 0, 0, 0};
    uint4* r = (uint4*)(rgbcp + pos * C2);
    #pragma unroll
    for (int i = 0; i < 32; ++i) r[i] = z;
    uint4* h = (uint4*)(hdnp + pos * MID);
    #pragma unroll
    for (int i = 0; i < 8; ++i) h[i] = z;
}

// ---------------- pack concat(rgb,thermal) NCHW fp32 -> padded NHWC bf16 ------
__global__ __launch_bounds__(256) void pack_rgbc(
    const float* __restrict__ rgb, const float* __restrict__ thermal,
    unsigned short* __restrict__ rgbcp)
{
    const int bid = blockIdx.x;
    const int ct  = bid & 7;
    const int rem = bid >> 3;
    const int y = rem % HH, b = rem / HH;
    const float* src = (ct < 4) ? rgb : thermal;
    const int cbase = (ct & 3) * 32;

    __shared__ float tile[32][81];
    for (int e = threadIdx.x; e < 32 * WW; e += 256) {
        int c = e / WW, x = e - c * WW;
        tile[c][x] = src[((size_t)(b * CIN + cbase + c) * HH + y) * WW + x];
    }
    __syncthreads();
    for (int e = threadIdx.x; e < 16 * WW; e += 256) {
        int x = e >> 4, cp = (e & 15) * 2;
        unsigned lo = f2bf(tile[cp][x]);
        unsigned hi = f2bf(tile[cp + 1][x]);
        *(unsigned*)(rgbcp + ((size_t)b * PP + (size_t)(y + 1) * PD + x + 1) * C2 + ct * 32 + cp)
            = lo | (hi << 16);
    }
}

// ---------------- weight packs ----------------
__global__ __launch_bounds__(256) void pack_w1(
    const float* __restrict__ w1, unsigned short* __restrict__ w1T)
{
    int idx = blockIdx.x * 256 + threadIdx.x;      // 9*64*256
    int tap = idx / (MID * C2);
    int rem = idx - tap * (MID * C2);
    int oc = rem / C2, ic = rem - (rem / C2) * C2;
    w1T[idx] = f2bf(w1[((size_t)oc * C2 + ic) * 9 + tap]);
}

__global__ __launch_bounds__(256) void pack_w2(
    const float* __restrict__ w2, unsigned short* __restrict__ w2T)
{
    int idx = blockIdx.x * 256 + threadIdx.x;      // 9*80*64
    int tap = idx / (80 * MID);
    int rem = idx - tap * (80 * MID);
    int oc = rem / MID, ic = rem - (rem / MID) * MID;
    float v = (oc < OFFC) ? w2[((size_t)oc * MID + ic) * 9 + tap] : 0.f;
    w2T[idx] = f2bf(v);
}

__global__ __launch_bounds__(256) void transpose_dw_kernel(
    const float* __restrict__ dw, float* __restrict__ dwT)
{
    int idx = blockIdx.x * 256 + threadIdx.x;
    if (idx >= NG * 9 * CG * CG) return;
    int oc  = idx & 31;
    int c   = (idx >> 5) & 31;
    int tap = (idx >> 10) % 9;
    int g   = idx / (9 * 1024);
    dwT[idx] = dw[((size_t)(g * CG + oc) * CG + c) * 9 + tap];
}

// ---------------- conv1: implicit GEMM, bf16 MFMA, ky-split across waves ------
// grid: B*H; block 768 = 12 waves = 4 nf (16 oc each) x 3 kyw (kernel row)
__global__ __launch_bounds__(768, 6) void conv1_mfma(
    const unsigned short* __restrict__ rgbcp, const unsigned short* __restrict__ w1T,
    const float* __restrict__ b1, unsigned short* __restrict__ hdnp)
{
    const int by = blockIdx.x;
    const int b = by / HH, y = by - b * HH;
    const int tid = threadIdx.x;
    const int wave = tid >> 6;
    const int nf  = wave & 3;       // oc fragment
    const int kyw = wave >> 2;      // kernel row 0..2  (ky = kyw-1)
    const int l = tid & 63, l15 = l & 15, lk = l >> 4;

    f32x4 acc[5];
    #pragma unroll
    for (int i = 0; i < 5; ++i) acc[i] = (f32x4){0.f, 0.f, 0.f, 0.f};

    // input row for this wave: padded row (y+1) + (kyw-1) = y + kyw
    const unsigned short* abase =
        rgbcp + ((size_t)b * PP + (size_t)(y + kyw) * PD + (l15 + 1)) * C2 + lk * 8;
    const unsigned short* bbase = w1T + ((size_t)(nf * 16 + l15)) * C2 + lk * 8;

    #pragma unroll
    for (int kxi = 0; kxi < 3; ++kxi) {
        const int tap = kyw * 3 + kxi;
        const unsigned short* at = abase + (kxi - 1) * C2;
        const unsigned short* bt = bbase + (size_t)tap * MID * C2;
        #pragma unroll
        for (int cb = 0; cb < 8; ++cb) {
            bf16x8 bf = *(const bf16x8*)(bt + cb * 32);
            #pragma unroll
            for (int mf = 0; mf < 5; ++mf) {
                bf16x8 af = *(const bf16x8*)(at + cb * 32 + mf * 16 * C2);
                acc[mf] = __builtin_amdgcn_mfma_f32_16x16x32_bf16(af, bf, acc[mf], 0, 0, 0);
            }
        }
    }

    // ky-partial reduction through LDS: waves kyw=1,2 publish, kyw=0 sums.
    __shared__ f32x4 red[2][4][5][64];   // 40 KB
    if (kyw > 0) {
        #pragma unroll
        for (int mf = 0; mf < 5; ++mf) red[kyw - 1][nf][mf][l] = acc[mf];
    }
    __syncthreads();
    if (kyw == 0) {
        #pragma unroll
        for (int mf = 0; mf < 5; ++mf) {
            f32x4 r0 = red[0][nf][mf][l];
            f32x4 r1 = red[1][nf][mf][l];
            #pragma unroll
            for (int r = 0; r < 4; ++r) acc[mf][r] += r0[r] + r1[r];
        }
        const int oc = nf * 16 + l15;
        const float bias = b1[oc];
        unsigned short* ob = hdnp + ((size_t)b * PP + (size_t)(y + 1) * PD + 1) * MID + oc;
        #pragma unroll
        for (int mf = 0; mf < 5; ++mf)
            #pragma unroll
            for (int r = 0; r < 4; ++r) {
                float v = acc[mf][r] + bias;
                v = v > 0.f ? v : 0.f;
                ob[(size_t)(mf * 16 + lk * 4 + r) * MID] = f2bf(v);
            }
    }
}

// ---------------- conv2: implicit GEMM, bf16 MFMA, scale, write NCHW fp32 -----
// grid: B*H, block 320 (5 waves); wave = nf (16 oc of 80 padded), 5 m-frags
__global__ __launch_bounds__(320) void conv2_mfma(
    const unsigned short* __restrict__ hdnp, const unsigned short* __restrict__ w2T,
    const float* __restrict__ b2, const float* __restrict__ scale_p,
    float* __restrict__ offs)
{
    const int by = blockIdx.x;
    const int b = by / HH, y = by - b * HH;
    const int tid = threadIdx.x;
    const int nf = tid >> 6;
    const int l = tid & 63, l15 = l & 15, lk = l >> 4;

    f32x4 acc[5];
    #pragma unroll
    for (int i = 0; i < 5; ++i) acc[i] = (f32x4){0.f, 0.f, 0.f, 0.f};

    const unsigned short* abase =
        hdnp + ((size_t)b * PP + (size_t)(y + 1) * PD + (l15 + 1)) * MID + lk * 8;
    const unsigned short* bbase = w2T + ((size_t)(nf * 16 + l15)) * MID + lk * 8;

    #pragma unroll
    for (int tap = 0; tap < 9; ++tap) {
        const int ky = tap / 3 - 1, kx = tap - (tap / 3) * 3 - 1;
        const unsigned short* at = abase + (ky * PD + kx) * MID;
        const unsigned short* bt = bbase + (size_t)tap * 80 * MID;
        #pragma unroll
        for (int cb = 0; cb < 2; ++cb) {
            bf16x8 bf = *(const bf16x8*)(bt + cb * 32);
            #pragma unroll
            for (int mf = 0; mf < 5; ++mf) {
                bf16x8 af = *(const bf16x8*)(at + cb * 32 + mf * 16 * MID);
                acc[mf] = __builtin_amdgcn_mfma_f32_16x16x32_bf16(af, bf, acc[mf], 0, 0, 0);
            }
        }
    }

    const int oc = nf * 16 + l15;
    if (oc < OFFC) {
        const float scale = scale_p[0];
        const float bias = b2[oc];
        float* ob = offs + ((size_t)b * OFFC + oc) * HW + y * WW;
        #pragma unroll
        for (int mf = 0; mf < 5; ++mf) {
            float4 v;
            v.x = (acc[mf][0] + bias) * scale;
            v.y = (acc[mf][1] + bias) * scale;
            v.z = (acc[mf][2] + bias) * scale;
            v.w = (acc[mf][3] + bias) * scale;
            *(float4*)(ob + mf * 16 + lk * 4) = v;
        }
    }
}

// ---------------- deformable conv 3x3, groups=4, bf16 NHWC gathers ----------
__global__ __launch_bounds__(256) void deform_kernel(
    const unsigned short* __restrict__ rgbcp, const float* __restrict__ offs,
    const float* __restrict__ dwT, const float* __restrict__ db,
    float* __restrict__ out)
{
    const int bid = blockIdx.x;
    const int pt  = bid % 25;
    const int rem = bid / 25;
    const int g   = rem & 3;
    const int b   = rem >> 2;
    const int p   = pt * 256 + threadIdx.x;
    const int y   = p / WW;
    const int x   = p - y * WW;

    float acc[32];
    #pragma unroll
    for (int i = 0; i < 32; ++i) acc[i] = 0.f;

    const unsigned short* gb = rgbcp + (size_t)b * PP * C2 + g * CG;
    const float* wg = dwT + (size_t)g * 9 * CG * CG;
    const float* ob = offs + ((size_t)b * OFFC + g * 18) * HW + p;

    for (int tap = 0; tap < 9; ++tap) {
        const int ky = tap / 3 - 1;
        const int kx = tap - (tap / 3) * 3 - 1;
        float offy = ob[(size_t)(2 * tap) * HW];
        float offx = ob[(size_t)(2 * tap + 1) * HW];
        float sy = (float)(y + ky) + offy;
        float sx = (float)(x + kx) + offx;
        float fy = floorf(sy), fx = floorf(sx);
        int iy = (int)fy, ix = (int)fx;
        float wy = sy - fy, wx = sx - fx;
        float w00 = (1.f - wy) * (1.f - wx);
        float w01 = (1.f - wy) * wx;
        float w10 = wy * (1.f - wx);
        float w11 = wy * wx;

        float samp[32];
        #pragma unroll
        for (int i = 0; i < 32; ++i) samp[i] = 0.f;

        const bool v0 = (unsigned)iy < HH;
        const bool v1 = (unsigned)(iy + 1) < HH;
        const bool u0 = (unsigned)ix < WW;
        const bool u1 = (unsigned)(ix + 1) < WW;
        const unsigned short* r00 = gb + ((size_t)(iy + 1) * PD + (ix + 1)) * C2;

        auto addc = [&](const unsigned short* base, float wgt) {
            const unsigned* pw = reinterpret_cast<const unsigned*>(base);
            #pragma unroll
            for (int q = 0; q < 16; ++q) {
                unsigned u = pw[q];
                float f0 = __uint_as_float(u << 16);
                float f1 = __uint_as_float(u & 0xffff0000u);
                samp[2 * q]     = fmaf(f0, wgt, samp[2 * q]);
                samp[2 * q + 1] = fmaf(f1, wgt, samp[2 * q + 1]);
            }
        };
        if (v0 && u0) addc(r00, w00);
        if (v0 && u1) addc(r00 + C2, w01);
        if (v1 && u0) addc(r00 + PD * C2, w10);
        if (v1 && u1) addc(r00 + (PD + 1) * C2, w11);

        const float* wtap = wg + tap * CG * CG;
        #pragma unroll
        for (int c = 0; c < 32; ++c) {
            float s = samp[c];
            #pragma unroll
            for (int oc = 0; oc < 32; ++oc)
                acc[oc] = fmaf(s, wtap[c * 32 + oc], acc[oc]);
        }
    }

    const size_t obase = ((size_t)b * CIN + g * CG) * HW + p;
    #pragma unroll
    for (int oc = 0; oc < 32; ++oc)
        out[obase + (size_t)oc * HW] = acc[oc] + db[g * CG + oc];
}

extern "C" void kernel_launch(void* const* d_in, const int* in_sizes, int n_in,
                              void* d_out, int out_size, void* d_ws, size_t ws_size,
                              hipStream_t stream) {
    const float* rgb     = (const float*)d_in[0];
    const float* thermal = (const float*)d_in[1];
    const float* w1      = (const float*)d_in[2];
    const float* b1      = (const float*)d_in[3];
    const float* w2      = (const float*)d_in[4];
    const float* b2      = (const float*)d_in[5];
    const float* dw      = (const float*)d_in[6];
    const float* db      = (const float*)d_in[7];
    const float* osc     = (const float*)d_in[8];

    char* w = (char*)d_ws;
    unsigned short* rgbcp = (unsigned short*)w;  w += (size_t)BB * PP * C2 * 2;
    unsigned short* hdnp  = (unsigned short*)w;  w += (size_t)BB * PP * MID * 2;
    float*          offs  = (float*)w;           w += (size_t)BB * OFFC * HW * 4;
    unsigned short* w1T   = (unsigned short*)w;  w += (size_t)9 * MID * C2 * 2;
    unsigned short* w2T   = (unsigned short*)w;  w += (size_t)9 * 80 * MID * 2;
    float*          dwT   = (float*)w;           w += (size_t)NG * 9 * CG * CG * 4;
    float* out = (float*)d_out;

    zero_borders<<<dim3((BB * 324 + 255) / 256), 256, 0, stream>>>(rgbcp, hdnp);
    pack_rgbc<<<dim3(BB * HH * 8), 256, 0, stream>>>(rgb, thermal, rgbcp);
    pack_w1<<<dim3(9 * MID * C2 / 256), 256, 0, stream>>>(w1, w1T);
    pack_w2<<<dim3(9 * 80 * MID / 256), 256, 0, stream>>>(w2, w2T);
    transpose_dw_kernel<<<dim3((NG * 9 * CG * CG + 255) / 256), 256, 0, stream>>>(dw, dwT);
    conv1_mfma<<<dim3(BB * HH), 768, 0, stream>>>(rgbcp, w1T, b1, hdnp);
    conv2_mfma<<<dim3(BB * HH), 320, 0, stream>>>(hdnp, w2T, b2, osc, offs);
    deform_kernel<<<dim3(BB * NG * 25), 256, 0, stream>>>(rgbcp, offs, dwT, db, out);
}

// Round 5
// 163.190 us; speedup vs baseline: 1.8974x; 1.8974x over previous
//
#include <hip/hip_runtime.h>

#define HH 80
#define WW 80
#define BB 8
#define CIN 128
#define C2 256
#define MID 64
#define OFFC 72
#define NG 4
#define CG 32
#define HW (HH * WW)
#define PD 82           // padded spatial dim
#define PP (PD * PD)    // padded pixels per image
#define STP 72          // LDS px stride in channels (144B, 16B-aligned, even banks)

typedef short bf16x8 __attribute__((ext_vector_type(8)));
typedef float f32x4  __attribute__((ext_vector_type(4)));

static __device__ __forceinline__ unsigned short f2bf(float f) {
    union { float f; unsigned u; } v; v.f = f;
    unsigned r = v.u + 0x7fffu + ((v.u >> 16) & 1u);   // RNE
    return (unsigned short)(r >> 16);
}

// ---------------- zero the 1-px border of padded bf16 buffers (every call) ----
__global__ __launch_bounds__(256) void zero_borders(
    unsigned short* __restrict__ rgbcp, unsigned short* __restrict__ hdnp)
{
    int idx = blockIdx.x * 256 + threadIdx.x;
    if (idx >= BB * 324) return;
    int b = idx / 324, e = idx - (idx / 324) * 324;
    int y, x;
    if (e < 82)       { y = 0;  x = e; }
    else if (e < 164) { y = 81; x = e - 82; }
    else if (e < 244) { y = e - 164 + 1; x = 0; }
    else              { y = e - 244 + 1; x = 81; }
    size_t pos = (size_t)b * PP + y * PD + x;
    uint4 z = {0, 0, 0, 0};
    uint4* r = (uint4*)(rgbcp + pos * C2);
    #pragma unroll
    for (int i = 0; i < 32; ++i) r[i] = z;
    uint4* h = (uint4*)(hdnp + pos * MID);
    #pragma unroll
    for (int i = 0; i < 8; ++i) h[i] = z;
}

// ---------------- pack concat(rgb,thermal) NCHW fp32 -> padded NHWC bf16 ------
__global__ __launch_bounds__(256) void pack_rgbc(
    const float* __restrict__ rgb, const float* __restrict__ thermal,
    unsigned short* __restrict__ rgbcp)
{
    const int bid = blockIdx.x;
    const int ct  = bid & 7;
    const int rem = bid >> 3;
    const int y = rem % HH, b = rem / HH;
    const float* src = (ct < 4) ? rgb : thermal;
    const int cbase = (ct & 3) * 32;

    __shared__ float tile[32][81];
    for (int e = threadIdx.x; e < 32 * WW; e += 256) {
        int c = e / WW, x = e - c * WW;
        tile[c][x] = src[((size_t)(b * CIN + cbase + c) * HH + y) * WW + x];
    }
    __syncthreads();
    for (int e = threadIdx.x; e < 16 * WW; e += 256) {
        int x = e >> 4, cp = (e & 15) * 2;
        unsigned lo = f2bf(tile[cp][x]);
        unsigned hi = f2bf(tile[cp + 1][x]);
        *(unsigned*)(rgbcp + ((size_t)b * PP + (size_t)(y + 1) * PD + x + 1) * C2 + ct * 32 + cp)
            = lo | (hi << 16);
    }
}

// ---------------- weight packs into MFMA fragment order ----------------
// w1F[nf4][cc4][tap9][cb2][lane64][e8] ; oc=nf*16+(l&15), ic=cc*64+cb*32+(l>>4)*8+e
__global__ __launch_bounds__(256) void pack_w1f(
    const float* __restrict__ w1, unsigned short* __restrict__ w1F)
{
    int idx = blockIdx.x * 256 + threadIdx.x;      // 147456
    int e  = idx & 7;
    int t1 = idx >> 3;  int l  = t1 & 63;
    int t2 = t1 >> 6;   int cb = t2 & 1;
    int t3 = t2 >> 1;   int tap = t3 % 9;
    int t4 = t3 / 9;    int cc = t4 & 3;  int nf = t4 >> 2;
    int oc = nf * 16 + (l & 15);
    int ic = cc * 64 + cb * 32 + (l >> 4) * 8 + e;
    w1F[idx] = f2bf(w1[((size_t)oc * C2 + ic) * 9 + tap]);
}

// w2F[nf5][tap9][cb2][lane64][e8] ; oc=nf*16+(l&15) (>=72 -> 0), ic=cb*32+(l>>4)*8+e
__global__ __launch_bounds__(256) void pack_w2f(
    const float* __restrict__ w2, unsigned short* __restrict__ w2F)
{
    int idx = blockIdx.x * 256 + threadIdx.x;      // 46080
    int e  = idx & 7;
    int t1 = idx >> 3;  int l  = t1 & 63;
    int t2 = t1 >> 6;   int cb = t2 & 1;
    int t3 = t2 >> 1;   int tap = t3 % 9;
    int nf = t3 / 9;
    int oc = nf * 16 + (l & 15);
    int ic = cb * 32 + (l >> 4) * 8 + e;
    float v = (oc < OFFC) ? w2[((size_t)oc * MID + ic) * 9 + tap] : 0.f;
    w2F[idx] = f2bf(v);
}

__global__ __launch_bounds__(256) void transpose_dw_kernel(
    const float* __restrict__ dw, float* __restrict__ dwT)
{
    int idx = blockIdx.x * 256 + threadIdx.x;
    if (idx >= NG * 9 * CG * CG) return;
    int oc  = idx & 31;
    int c   = (idx >> 5) & 31;
    int tap = (idx >> 10) % 9;
    int g   = idx / (9 * 1024);
    dwT[idx] = dw[((size_t)(g * CG + oc) * CG + c) * 9 + tap];
}

// ---------------- conv1: implicit GEMM, LDS-staged A, fragment-packed B -------
// grid: B*H; block 256 = 4 waves (nf = 16 oc each); K = 4 chunks of 64 ch
__global__ __launch_bounds__(256) void conv1_mfma(
    const unsigned short* __restrict__ rgbcp, const unsigned short* __restrict__ w1F,
    const float* __restrict__ b1, unsigned short* __restrict__ hdnp)
{
    const int by = blockIdx.x;
    const int b = by / HH, y = by - b * HH;
    const int tid = threadIdx.x;
    const int nf = tid >> 6;
    const int l = tid & 63, l15 = l & 15, lk = l >> 4;

    __shared__ __align__(16) unsigned short st[3 * 82 * STP];   // 35.4 KB

    f32x4 acc[5];
    #pragma unroll
    for (int i = 0; i < 5; ++i) acc[i] = (f32x4){0.f, 0.f, 0.f, 0.f};

    const size_t rowbase = (size_t)b * PP + (size_t)y * PD;   // padded row y = out row -1

    for (int cc = 0; cc < 4; ++cc) {
        __syncthreads();
        // stage 3 rows x 82 px x 64 ch, dense coalesced 16B units
        for (int e = tid; e < 3 * 82 * 8; e += 256) {
            int r   = e / 656;
            int rem = e - r * 656;
            int px  = rem >> 3;
            int c8  = rem & 7;
            const uint4 v = *(const uint4*)(rgbcp + (rowbase + (size_t)r * PD + px) * C2 + cc * 64 + c8 * 8);
            *(uint4*)&st[(r * 82 + px) * STP + c8 * 8] = v;
        }
        __syncthreads();

        const unsigned short* bw = w1F + (((size_t)(nf * 4 + cc) * 9) * 2 * 64) * 8;
        #pragma unroll
        for (int tap = 0; tap < 9; ++tap) {
            const int ky = tap / 3, kx = tap - ky * 3;
            #pragma unroll
            for (int cb = 0; cb < 2; ++cb) {
                bf16x8 bf = *(const bf16x8*)(bw + ((size_t)(tap * 2 + cb) * 64 + l) * 8);
                #pragma unroll
                for (int mf = 0; mf < 5; ++mf) {
                    bf16x8 af = *(const bf16x8*)&st[(ky * 82 + mf * 16 + l15 + kx) * STP + cb * 32 + lk * 8];
                    acc[mf] = __builtin_amdgcn_mfma_f32_16x16x32_bf16(af, bf, acc[mf], 0, 0, 0);
                }
            }
        }
    }

    const int oc = nf * 16 + l15;
    const float bias = b1[oc];
    unsigned short* ob = hdnp + ((size_t)b * PP + (size_t)(y + 1) * PD + 1) * MID + oc;
    #pragma unroll
    for (int mf = 0; mf < 5; ++mf)
        #pragma unroll
        for (int r = 0; r < 4; ++r) {
            float v = acc[mf][r] + bias;
            v = v > 0.f ? v : 0.f;
            ob[(size_t)(mf * 16 + lk * 4 + r) * MID] = f2bf(v);
        }
}

// ---------------- conv2: implicit GEMM, LDS-staged A, fragment-packed B -------
// grid: B*H; block 320 = 5 waves (nf = 16 oc of 80 padded); K = 576, one chunk
__global__ __launch_bounds__(320) void conv2_mfma(
    const unsigned short* __restrict__ hdnp, const unsigned short* __restrict__ w2F,
    const float* __restrict__ b2, const float* __restrict__ scale_p,
    float* __restrict__ offs)
{
    const int by = blockIdx.x;
    const int b = by / HH, y = by - b * HH;
    const int tid = threadIdx.x;
    const int nf = tid / 64;
    const int l = tid & 63, l15 = l & 15, lk = l >> 4;

    __shared__ __align__(16) unsigned short st[3 * 82 * STP];

    f32x4 acc[5];
    #pragma unroll
    for (int i = 0; i < 5; ++i) acc[i] = (f32x4){0.f, 0.f, 0.f, 0.f};

    const size_t rowbase = (size_t)b * PP + (size_t)y * PD;

    for (int e = tid; e < 3 * 82 * 8; e += 320) {
        int r   = e / 656;
        int rem = e - r * 656;
        int px  = rem >> 3;
        int c8  = rem & 7;
        const uint4 v = *(const uint4*)(hdnp + (rowbase + (size_t)r * PD + px) * MID + c8 * 8);
        *(uint4*)&st[(r * 82 + px) * STP + c8 * 8] = v;
    }
    __syncthreads();

    const unsigned short* bw = w2F + ((size_t)nf * 9 * 2 * 64) * 8;
    #pragma unroll
    for (int tap = 0; tap < 9; ++tap) {
        const int ky = tap / 3, kx = tap - ky * 3;
        #pragma unroll
        for (int cb = 0; cb < 2; ++cb) {
            bf16x8 bf = *(const bf16x8*)(bw + ((size_t)(tap * 2 + cb) * 64 + l) * 8);
            #pragma unroll
            for (int mf = 0; mf < 5; ++mf) {
                bf16x8 af = *(const bf16x8*)&st[(ky * 82 + mf * 16 + l15 + kx) * STP + cb * 32 + lk * 8];
                acc[mf] = __builtin_amdgcn_mfma_f32_16x16x32_bf16(af, bf, acc[mf], 0, 0, 0);
            }
        }
    }

    const int oc = nf * 16 + l15;
    if (oc < OFFC) {
        const float scale = scale_p[0];
        const float bias = b2[oc];
        float* ob = offs + ((size_t)b * OFFC + oc) * HW + y * WW;
        #pragma unroll
        for (int mf = 0; mf < 5; ++mf) {
            float4 v;
            v.x = (acc[mf][0] + bias) * scale;
            v.y = (acc[mf][1] + bias) * scale;
            v.z = (acc[mf][2] + bias) * scale;
            v.w = (acc[mf][3] + bias) * scale;
            *(float4*)(ob + mf * 16 + lk * 4) = v;
        }
    }
}

// ---------------- deformable conv 3x3, groups=4, bf16 NHWC gathers ----------
__global__ __launch_bounds__(256) void deform_kernel(
    const unsigned short* __restrict__ rgbcp, const float* __restrict__ offs,
    const float* __restrict__ dwT, const float* __restrict__ db,
    float* __restrict__ out)
{
    const int bid = blockIdx.x;
    const int pt  = bid % 25;
    const int rem = bid / 25;
    const int g   = rem & 3;
    const int b   = rem >> 2;
    const int p   = pt * 256 + threadIdx.x;
    const int y   = p / WW;
    const int x   = p - y * WW;

    float acc[32];
    #pragma unroll
    for (int i = 0; i < 32; ++i) acc[i] = 0.f;

    const unsigned short* gb = rgbcp + (size_t)b * PP * C2 + g * CG;
    const float* wg = dwT + (size_t)g * 9 * CG * CG;
    const float* ob = offs + ((size_t)b * OFFC + g * 18) * HW + p;

    for (int tap = 0; tap < 9; ++tap) {
        const int ky = tap / 3 - 1;
        const int kx = tap - (tap / 3) * 3 - 1;
        float offy = ob[(size_t)(2 * tap) * HW];
        float offx = ob[(size_t)(2 * tap + 1) * HW];
        float sy = (float)(y + ky) + offy;
        float sx = (float)(x + kx) + offx;
        float fy = floorf(sy), fx = floorf(sx);
        int iy = (int)fy, ix = (int)fx;
        float wy = sy - fy, wx = sx - fx;
        float w00 = (1.f - wy) * (1.f - wx);
        float w01 = (1.f - wy) * wx;
        float w10 = wy * (1.f - wx);
        float w11 = wy * wx;

        float samp[32];
        #pragma unroll
        for (int i = 0; i < 32; ++i) samp[i] = 0.f;

        const bool v0 = (unsigned)iy < HH;
        const bool v1 = (unsigned)(iy + 1) < HH;
        const bool u0 = (unsigned)ix < WW;
        const bool u1 = (unsigned)(ix + 1) < WW;
        const unsigned short* r00 = gb + ((size_t)(iy + 1) * PD + (ix + 1)) * C2;

        auto addc = [&](const unsigned short* base, float wgt) {
            const unsigned* pw = reinterpret_cast<const unsigned*>(base);
            #pragma unroll
            for (int q = 0; q < 16; ++q) {
                unsigned u = pw[q];
                float f0 = __uint_as_float(u << 16);
                float f1 = __uint_as_float(u & 0xffff0000u);
                samp[2 * q]     = fmaf(f0, wgt, samp[2 * q]);
                samp[2 * q + 1] = fmaf(f1, wgt, samp[2 * q + 1]);
            }
        };
        if (v0 && u0) addc(r00, w00);
        if (v0 && u1) addc(r00 + C2, w01);
        if (v1 && u0) addc(r00 + PD * C2, w10);
        if (v1 && u1) addc(r00 + (PD + 1) * C2, w11);

        const float* wtap = wg + tap * CG * CG;
        #pragma unroll
        for (int c = 0; c < 32; ++c) {
            float s = samp[c];
            #pragma unroll
            for (int oc = 0; oc < 32; ++oc)
                acc[oc] = fmaf(s, wtap[c * 32 + oc], acc[oc]);
        }
    }

    const size_t obase = ((size_t)b * CIN + g * CG) * HW + p;
    #pragma unroll
    for (int oc = 0; oc < 32; ++oc)
        out[obase + (size_t)oc * HW] = acc[oc] + db[g * CG + oc];
}

extern "C" void kernel_launch(void* const* d_in, const int* in_sizes, int n_in,
                              void* d_out, int out_size, void* d_ws, size_t ws_size,
                              hipStream_t stream) {
    const float* rgb     = (const float*)d_in[0];
    const float* thermal = (const float*)d_in[1];
    const float* w1      = (const float*)d_in[2];
    const float* b1      = (const float*)d_in[3];
    const float* w2      = (const float*)d_in[4];
    const float* b2      = (const float*)d_in[5];
    const float* dw      = (const float*)d_in[6];
    const float* db      = (const float*)d_in[7];
    const float* osc     = (const float*)d_in[8];

    char* w = (char*)d_ws;
    unsigned short* rgbcp = (unsigned short*)w;  w += (size_t)BB * PP * C2 * 2;
    unsigned short* hdnp  = (unsigned short*)w;  w += (size_t)BB * PP * MID * 2;
    float*          offs  = (float*)w;           w += (size_t)BB * OFFC * HW * 4;
    unsigned short* w1F   = (unsigned short*)w;  w += (size_t)4 * 4 * 9 * 2 * 64 * 8 * 2;
    unsigned short* w2F   = (unsigned short*)w;  w += (size_t)5 * 9 * 2 * 64 * 8 * 2;
    float*          dwT   = (float*)w;           w += (size_t)NG * 9 * CG * CG * 4;
    float* out = (float*)d_out;

    zero_borders<<<dim3((BB * 324 + 255) / 256), 256, 0, stream>>>(rgbcp, hdnp);
    pack_rgbc<<<dim3(BB * HH * 8), 256, 0, stream>>>(rgb, thermal, rgbcp);
    pack_w1f<<<dim3(147456 / 256), 256, 0, stream>>>(w1, w1F);
    pack_w2f<<<dim3(46080 / 256), 256, 0, stream>>>(w2, w2F);
    transpose_dw_kernel<<<dim3((NG * 9 * CG * CG + 255) / 256), 256, 0, stream>>>(dw, dwT);
    conv1_mfma<<<dim3(BB * HH), 256, 0, stream>>>(rgbcp, w1F, b1, hdnp);
    conv2_mfma<<<dim3(BB * HH), 320, 0, stream>>>(hdnp, w2F, b2, osc, offs);
    deform_kernel<<<dim3(BB * NG * 25), 256, 0, stream>>>(rgbcp, offs, dwT, db, out);
}

// Round 6
// 139.602 us; speedup vs baseline: 2.2180x; 1.1690x over previous
//
#include <hip/hip_runtime.h>

#define HH 80
#define WW 80
#define BB 8
#define CIN 128
#define C2 256
#define MID 64
#define OFFC 72
#define NG 4
#define CG 32
#define HW (HH * WW)
#define PD 82           // padded spatial dim
#define PP (PD * PD)    // padded pixels per image
#define STP 72          // LDS px stride in channels (144B, 16B-aligned, even banks)

typedef short bf16x8 __attribute__((ext_vector_type(8)));
typedef float f32x4  __attribute__((ext_vector_type(4)));

static __device__ __forceinline__ unsigned short f2bf(float f) {
    union { float f; unsigned u; } v; v.f = f;
    unsigned r = v.u + 0x7fffu + ((v.u >> 16) & 1u);   // RNE
    return (unsigned short)(r >> 16);
}

// ---------------- zero the 1-px border of padded bf16 buffers (every call) ----
__global__ __launch_bounds__(256) void zero_borders(
    unsigned short* __restrict__ rgbcp, unsigned short* __restrict__ hdnp)
{
    int idx = blockIdx.x * 256 + threadIdx.x;
    if (idx >= BB * 324) return;
    int b = idx / 324, e = idx - (idx / 324) * 324;
    int y, x;
    if (e < 82)       { y = 0;  x = e; }
    else if (e < 164) { y = 81; x = e - 82; }
    else if (e < 244) { y = e - 164 + 1; x = 0; }
    else              { y = e - 244 + 1; x = 81; }
    size_t pos = (size_t)b * PP + y * PD + x;
    uint4 z = {0, 0, 0, 0};
    uint4* r = (uint4*)(rgbcp + pos * C2);
    #pragma unroll
    for (int i = 0; i < 32; ++i) r[i] = z;
    uint4* h = (uint4*)(hdnp + pos * MID);
    #pragma unroll
    for (int i = 0; i < 8; ++i) h[i] = z;
}

// ---------------- pack concat(rgb,thermal) NCHW fp32 -> padded NHWC bf16 ------
__global__ __launch_bounds__(256) void pack_rgbc(
    const float* __restrict__ rgb, const float* __restrict__ thermal,
    unsigned short* __restrict__ rgbcp)
{
    const int bid = blockIdx.x;
    const int ct  = bid & 7;
    const int rem = bid >> 3;
    const int y = rem % HH, b = rem / HH;
    const float* src = (ct < 4) ? rgb : thermal;
    const int cbase = (ct & 3) * 32;

    __shared__ float tile[32][81];
    for (int e = threadIdx.x; e < 32 * WW; e += 256) {
        int c = e / WW, x = e - c * WW;
        tile[c][x] = src[((size_t)(b * CIN + cbase + c) * HH + y) * WW + x];
    }
    __syncthreads();
    for (int e = threadIdx.x; e < 16 * WW; e += 256) {
        int x = e >> 4, cp = (e & 15) * 2;
        unsigned lo = f2bf(tile[cp][x]);
        unsigned hi = f2bf(tile[cp + 1][x]);
        *(unsigned*)(rgbcp + ((size_t)b * PP + (size_t)(y + 1) * PD + x + 1) * C2 + ct * 32 + cp)
            = lo | (hi << 16);
    }
}

// ---------------- weight packs into MFMA fragment order ----------------
// w1F[nf4][cc4][tap9][cb2][lane64][e8] ; oc=nf*16+(l&15), ic=cc*64+cb*32+(l>>4)*8+e
__global__ __launch_bounds__(256) void pack_w1f(
    const float* __restrict__ w1, unsigned short* __restrict__ w1F)
{
    int idx = blockIdx.x * 256 + threadIdx.x;      // 147456
    int e  = idx & 7;
    int t1 = idx >> 3;  int l  = t1 & 63;
    int t2 = t1 >> 6;   int cb = t2 & 1;
    int t3 = t2 >> 1;   int tap = t3 % 9;
    int t4 = t3 / 9;    int cc = t4 & 3;  int nf = t4 >> 2;
    int oc = nf * 16 + (l & 15);
    int ic = cc * 64 + cb * 32 + (l >> 4) * 8 + e;
    w1F[idx] = f2bf(w1[((size_t)oc * C2 + ic) * 9 + tap]);
}

// w2F[nf5][tap9][cb2][lane64][e8] ; oc=nf*16+(l&15) (>=72 -> 0), ic=cb*32+(l>>4)*8+e
__global__ __launch_bounds__(256) void pack_w2f(
    const float* __restrict__ w2, unsigned short* __restrict__ w2F)
{
    int idx = blockIdx.x * 256 + threadIdx.x;      // 46080
    int e  = idx & 7;
    int t1 = idx >> 3;  int l  = t1 & 63;
    int t2 = t1 >> 6;   int cb = t2 & 1;
    int t3 = t2 >> 1;   int tap = t3 % 9;
    int nf = t3 / 9;
    int oc = nf * 16 + (l & 15);
    int ic = cb * 32 + (l >> 4) * 8 + e;
    float v = (oc < OFFC) ? w2[((size_t)oc * MID + ic) * 9 + tap] : 0.f;
    w2F[idx] = f2bf(v);
}

// dwF[g4][tap9][ocb2][lane64][e8] ; oc_local=ocb*16+(l&15), c=(l>>4)*8+e
__global__ __launch_bounds__(256) void pack_dwf(
    const float* __restrict__ dw, unsigned short* __restrict__ dwF)
{
    int idx = blockIdx.x * 256 + threadIdx.x;      // 36864
    int e   = idx & 7;
    int l   = (idx >> 3) & 63;
    int ocb = (idx >> 9) & 1;
    int gt  = idx >> 10;
    int tap = gt % 9, g = gt / 9;
    int oc = ocb * 16 + (l & 15);
    int c  = (l >> 4) * 8 + e;
    dwF[idx] = f2bf(dw[((size_t)(g * CG + oc) * CG + c) * 9 + tap]);
}

// ---------------- conv1: implicit GEMM, LDS-staged A, fragment-packed B -------
// grid: B*H; block 256 = 4 waves (nf = 16 oc each); K = 4 chunks of 64 ch
__global__ __launch_bounds__(256) void conv1_mfma(
    const unsigned short* __restrict__ rgbcp, const unsigned short* __restrict__ w1F,
    const float* __restrict__ b1, unsigned short* __restrict__ hdnp)
{
    const int by = blockIdx.x;
    const int b = by / HH, y = by - b * HH;
    const int tid = threadIdx.x;
    const int nf = tid >> 6;
    const int l = tid & 63, l15 = l & 15, lk = l >> 4;

    __shared__ __align__(16) unsigned short st[3 * 82 * STP];   // 35.4 KB

    f32x4 acc[5];
    #pragma unroll
    for (int i = 0; i < 5; ++i) acc[i] = (f32x4){0.f, 0.f, 0.f, 0.f};

    const size_t rowbase = (size_t)b * PP + (size_t)y * PD;   // padded row y = out row -1

    for (int cc = 0; cc < 4; ++cc) {
        __syncthreads();
        // stage 3 rows x 82 px x 64 ch, dense coalesced 16B units
        for (int e = tid; e < 3 * 82 * 8; e += 256) {
            int r   = e / 656;
            int rem = e - r * 656;
            int px  = rem >> 3;
            int c8  = rem & 7;
            const uint4 v = *(const uint4*)(rgbcp + (rowbase + (size_t)r * PD + px) * C2 + cc * 64 + c8 * 8);
            *(uint4*)&st[(r * 82 + px) * STP + c8 * 8] = v;
        }
        __syncthreads();

        const unsigned short* bw = w1F + (((size_t)(nf * 4 + cc) * 9) * 2 * 64) * 8;
        #pragma unroll
        for (int tap = 0; tap < 9; ++tap) {
            const int ky = tap / 3, kx = tap - ky * 3;
            #pragma unroll
            for (int cb = 0; cb < 2; ++cb) {
                bf16x8 bf = *(const bf16x8*)(bw + ((size_t)(tap * 2 + cb) * 64 + l) * 8);
                #pragma unroll
                for (int mf = 0; mf < 5; ++mf) {
                    bf16x8 af = *(const bf16x8*)&st[(ky * 82 + mf * 16 + l15 + kx) * STP + cb * 32 + lk * 8];
                    acc[mf] = __builtin_amdgcn_mfma_f32_16x16x32_bf16(af, bf, acc[mf], 0, 0, 0);
                }
            }
        }
    }

    const int oc = nf * 16 + l15;
    const float bias = b1[oc];
    unsigned short* ob = hdnp + ((size_t)b * PP + (size_t)(y + 1) * PD + 1) * MID + oc;
    #pragma unroll
    for (int mf = 0; mf < 5; ++mf)
        #pragma unroll
        for (int r = 0; r < 4; ++r) {
            float v = acc[mf][r] + bias;
            v = v > 0.f ? v : 0.f;
            ob[(size_t)(mf * 16 + lk * 4 + r) * MID] = f2bf(v);
        }
}

// ---------------- conv2: implicit GEMM, LDS-staged A, fragment-packed B -------
// grid: B*H; block 320 = 5 waves (nf = 16 oc of 80 padded); K = 576, one chunk
__global__ __launch_bounds__(320) void conv2_mfma(
    const unsigned short* __restrict__ hdnp, const unsigned short* __restrict__ w2F,
    const float* __restrict__ b2, const float* __restrict__ scale_p,
    float* __restrict__ offs)
{
    const int by = blockIdx.x;
    const int b = by / HH, y = by - b * HH;
    const int tid = threadIdx.x;
    const int nf = tid / 64;
    const int l = tid & 63, l15 = l & 15, lk = l >> 4;

    __shared__ __align__(16) unsigned short st[3 * 82 * STP];

    f32x4 acc[5];
    #pragma unroll
    for (int i = 0; i < 5; ++i) acc[i] = (f32x4){0.f, 0.f, 0.f, 0.f};

    const size_t rowbase = (size_t)b * PP + (size_t)y * PD;

    for (int e = tid; e < 3 * 82 * 8; e += 320) {
        int r   = e / 656;
        int rem = e - r * 656;
        int px  = rem >> 3;
        int c8  = rem & 7;
        const uint4 v = *(const uint4*)(hdnp + (rowbase + (size_t)r * PD + px) * MID + c8 * 8);
        *(uint4*)&st[(r * 82 + px) * STP + c8 * 8] = v;
    }
    __syncthreads();

    const unsigned short* bw = w2F + ((size_t)nf * 9 * 2 * 64) * 8;
    #pragma unroll
    for (int tap = 0; tap < 9; ++tap) {
        const int ky = tap / 3, kx = tap - ky * 3;
        #pragma unroll
        for (int cb = 0; cb < 2; ++cb) {
            bf16x8 bf = *(const bf16x8*)(bw + ((size_t)(tap * 2 + cb) * 64 + l) * 8);
            #pragma unroll
            for (int mf = 0; mf < 5; ++mf) {
                bf16x8 af = *(const bf16x8*)&st[(ky * 82 + mf * 16 + l15 + kx) * STP + cb * 32 + lk * 8];
                acc[mf] = __builtin_amdgcn_mfma_f32_16x16x32_bf16(af, bf, acc[mf], 0, 0, 0);
            }
        }
    }

    const int oc = nf * 16 + l15;
    if (oc < OFFC) {
        const float scale = scale_p[0];
        const float bias = b2[oc];
        float* ob = offs + ((size_t)b * OFFC + oc) * HW + y * WW;
        #pragma unroll
        for (int mf = 0; mf < 5; ++mf) {
            float4 v;
            v.x = (acc[mf][0] + bias) * scale;
            v.y = (acc[mf][1] + bias) * scale;
            v.z = (acc[mf][2] + bias) * scale;
            v.w = (acc[mf][3] + bias) * scale;
            *(float4*)(ob + mf * 16 + lk * 4) = v;
        }
    }
}

// ---------------- deformable conv 3x3, groups=4, MFMA channel mix ------------
// wave = 16 pixels x 1 group; block 256 = 4 waves; grid = B*NG*400/4 = 3200
__global__ __launch_bounds__(256) void deform_kernel(
    const unsigned short* __restrict__ rgbcp, const float* __restrict__ offs,
    const unsigned short* __restrict__ dwF, const float* __restrict__ db,
    float* __restrict__ out)
{
    const int w = blockIdx.x * 4 + (threadIdx.x >> 6);
    const int ptile = w % 400;
    const int rem = w / 400;
    const int g = rem & 3;
    const int b = rem >> 2;
    const int l = threadIdx.x & 63, l15 = l & 15, lk = l >> 4;

    const int p0 = ptile * 16;
    const int y  = p0 / WW;            // wave-uniform (80 % 16 == 0)
    const int x  = p0 - y * WW + l15;
    const int p  = p0 + l15;

    f32x4 acc[2];
    acc[0] = (f32x4){0.f, 0.f, 0.f, 0.f};
    acc[1] = (f32x4){0.f, 0.f, 0.f, 0.f};

    const unsigned short* gb = rgbcp + (size_t)b * PP * C2 + g * CG + lk * 8;
    const unsigned short* wg = dwF + (size_t)g * 9 * 2 * 64 * 8;
    const float* ob = offs + ((size_t)b * OFFC + g * 18) * HW + p;

    for (int tap = 0; tap < 9; ++tap) {
        const int ky = tap / 3 - 1;
        const int kx = tap - (tap / 3) * 3 - 1;
        float offy = ob[(size_t)(2 * tap) * HW];
        float offx = ob[(size_t)(2 * tap + 1) * HW];
        float sy = (float)(y + ky) + offy;
        float sx = (float)(x + kx) + offx;
        float fy = floorf(sy), fx = floorf(sx);
        int iy = (int)fy, ix = (int)fx;
        float wy = sy - fy, wx = sx - fx;

        float my0 = ((unsigned)iy       < HH) ? 1.f : 0.f;
        float my1 = ((unsigned)(iy + 1) < HH) ? 1.f : 0.f;
        float mx0 = ((unsigned)ix       < WW) ? 1.f : 0.f;
        float mx1 = ((unsigned)(ix + 1) < WW) ? 1.f : 0.f;
        float w00 = (1.f - wy) * (1.f - wx) * my0 * mx0;
        float w01 = (1.f - wy) * wx         * my0 * mx1;
        float w10 = wy * (1.f - wx)         * my1 * mx0;
        float w11 = wy * wx                 * my1 * mx1;

        int cy0 = min(max(iy, 0), HH - 1) + 1;
        int cy1 = min(max(iy + 1, 0), HH - 1) + 1;
        int cx0 = min(max(ix, 0), WW - 1) + 1;
        int cx1 = min(max(ix + 1, 0), WW - 1) + 1;

        float s[8];
        #pragma unroll
        for (int i = 0; i < 8; ++i) s[i] = 0.f;

        auto corner = [&](int cy, int cx, float wgt) {
            uint4 v = *(const uint4*)(gb + ((size_t)cy * PD + cx) * C2);
            unsigned u[4] = {v.x, v.y, v.z, v.w};
            #pragma unroll
            for (int j = 0; j < 4; ++j) {
                float f0 = __uint_as_float(u[j] << 16);
                float f1 = __uint_as_float(u[j] & 0xffff0000u);
                s[2 * j]     = fmaf(f0, wgt, s[2 * j]);
                s[2 * j + 1] = fmaf(f1, wgt, s[2 * j + 1]);
            }
        };
        corner(cy0, cx0, w00);
        corner(cy0, cx1, w01);
        corner(cy1, cx0, w10);
        corner(cy1, cx1, w11);

        union { bf16x8 v; unsigned u[4]; } af;
        #pragma unroll
        for (int j = 0; j < 4; ++j)
            asm volatile("v_cvt_pk_bf16_f32 %0, %1, %2"
                         : "=v"(af.u[j]) : "v"(s[2 * j]), "v"(s[2 * j + 1]));

        const unsigned short* wt = wg + (size_t)tap * 2 * 64 * 8;
        bf16x8 bf0 = *(const bf16x8*)(wt + (size_t)l * 8);
        bf16x8 bf1 = *(const bf16x8*)(wt + ((size_t)64 + l) * 8);
        acc[0] = __builtin_amdgcn_mfma_f32_16x16x32_bf16(af.v, bf0, acc[0], 0, 0, 0);
        acc[1] = __builtin_amdgcn_mfma_f32_16x16x32_bf16(af.v, bf1, acc[1], 0, 0, 0);
    }

    #pragma unroll
    for (int ocb = 0; ocb < 2; ++ocb) {
        const int oc = g * CG + ocb * 16 + l15;
        const float bias = db[oc];
        float4 v;
        v.x = acc[ocb][0] + bias;
        v.y = acc[ocb][1] + bias;
        v.z = acc[ocb][2] + bias;
        v.w = acc[ocb][3] + bias;
        *(float4*)(out + ((size_t)b * CIN + oc) * HW + p0 + lk * 4) = v;
    }
}

extern "C" void kernel_launch(void* const* d_in, const int* in_sizes, int n_in,
                              void* d_out, int out_size, void* d_ws, size_t ws_size,
                              hipStream_t stream) {
    const float* rgb     = (const float*)d_in[0];
    const float* thermal = (const float*)d_in[1];
    const float* w1      = (const float*)d_in[2];
    const float* b1      = (const float*)d_in[3];
    const float* w2      = (const float*)d_in[4];
    const float* b2      = (const float*)d_in[5];
    const float* dw      = (const float*)d_in[6];
    const float* db      = (const float*)d_in[7];
    const float* osc     = (const float*)d_in[8];

    char* w = (char*)d_ws;
    unsigned short* rgbcp = (unsigned short*)w;  w += (size_t)BB * PP * C2 * 2;
    unsigned short* hdnp  = (unsigned short*)w;  w += (size_t)BB * PP * MID * 2;
    float*          offs  = (float*)w;           w += (size_t)BB * OFFC * HW * 4;
    unsigned short* w1F   = (unsigned short*)w;  w += (size_t)4 * 4 * 9 * 2 * 64 * 8 * 2;
    unsigned short* w2F   = (unsigned short*)w;  w += (size_t)5 * 9 * 2 * 64 * 8 * 2;
    unsigned short* dwF   = (unsigned short*)w;  w += (size_t)4 * 9 * 2 * 64 * 8 * 2;
    float* out = (float*)d_out;

    zero_borders<<<dim3((BB * 324 + 255) / 256), 256, 0, stream>>>(rgbcp, hdnp);
    pack_rgbc<<<dim3(BB * HH * 8), 256, 0, stream>>>(rgb, thermal, rgbcp);
    pack_w1f<<<dim3(147456 / 256), 256, 0, stream>>>(w1, w1F);
    pack_w2f<<<dim3(46080 / 256), 256, 0, stream>>>(w2, w2F);
    pack_dwf<<<dim3(36864 / 256), 256, 0, stream>>>(dw, dwF);
    conv1_mfma<<<dim3(BB * HH), 256, 0, stream>>>(rgbcp, w1F, b1, hdnp);
    conv2_mfma<<<dim3(BB * HH), 320, 0, stream>>>(hdnp, w2F, b2, osc, offs);
    deform_kernel<<<dim3(BB * NG * 400 / 4), 256, 0, stream>>>(rgbcp, offs, dwF, db, out);
}

// Round 7
// 133.149 us; speedup vs baseline: 2.3255x; 1.0485x over previous
//
#include <hip/hip_runtime.h>

#define HH 80
#define WW 80
#define BB 8
#define CIN 128
#define C2 256
#define MID 64
#define OFFC 72
#define NG 4
#define CG 32
#define HW (HH * WW)
#define PD 82           // padded spatial dim
#define PP (PD * PD)    // padded pixels per image
#define STP 72          // LDS px stride in channels (144B, 16B-aligned, even banks)

typedef short bf16x8 __attribute__((ext_vector_type(8)));
typedef float f32x4  __attribute__((ext_vector_type(4)));

static __device__ __forceinline__ unsigned short f2bf(float f) {
    union { float f; unsigned u; } v; v.f = f;
    unsigned r = v.u + 0x7fffu + ((v.u >> 16) & 1u);   // RNE
    return (unsigned short)(r >> 16);
}

// ---------------- zero the 1-px border of padded bf16 buffers (every call) ----
__global__ __launch_bounds__(256) void zero_borders(
    unsigned short* __restrict__ rgbcp, unsigned short* __restrict__ hdnp)
{
    int idx = blockIdx.x * 256 + threadIdx.x;
    if (idx >= BB * 324) return;
    int b = idx / 324, e = idx - (idx / 324) * 324;
    int y, x;
    if (e < 82)       { y = 0;  x = e; }
    else if (e < 164) { y = 81; x = e - 82; }
    else if (e < 244) { y = e - 164 + 1; x = 0; }
    else              { y = e - 244 + 1; x = 81; }
    size_t pos = (size_t)b * PP + y * PD + x;
    uint4 z = {0, 0, 0, 0};
    uint4* r = (uint4*)(rgbcp + pos * C2);
    #pragma unroll
    for (int i = 0; i < 32; ++i) r[i] = z;
    uint4* h = (uint4*)(hdnp + pos * MID);
    #pragma unroll
    for (int i = 0; i < 8; ++i) h[i] = z;
}

// ---------------- pack concat(rgb,thermal) NCHW fp32 -> padded NHWC bf16 ------
__global__ __launch_bounds__(256) void pack_rgbc(
    const float* __restrict__ rgb, const float* __restrict__ thermal,
    unsigned short* __restrict__ rgbcp)
{
    const int bid = blockIdx.x;
    const int ct  = bid & 7;
    const int rem = bid >> 3;
    const int y = rem % HH, b = rem / HH;
    const float* src = (ct < 4) ? rgb : thermal;
    const int cbase = (ct & 3) * 32;

    __shared__ float tile[32][81];
    for (int e = threadIdx.x; e < 32 * WW; e += 256) {
        int c = e / WW, x = e - c * WW;
        tile[c][x] = src[((size_t)(b * CIN + cbase + c) * HH + y) * WW + x];
    }
    __syncthreads();
    for (int e = threadIdx.x; e < 16 * WW; e += 256) {
        int x = e >> 4, cp = (e & 15) * 2;
        unsigned lo = f2bf(tile[cp][x]);
        unsigned hi = f2bf(tile[cp + 1][x]);
        *(unsigned*)(rgbcp + ((size_t)b * PP + (size_t)(y + 1) * PD + x + 1) * C2 + ct * 32 + cp)
            = lo | (hi << 16);
    }
}

// ---------------- weight packs into MFMA fragment order ----------------
// w1F[nf4][cc4][tap9][cb2][lane64][e8] ; oc=nf*16+(l&15), ic=cc*64+cb*32+(l>>4)*8+e
__global__ __launch_bounds__(256) void pack_w1f(
    const float* __restrict__ w1, unsigned short* __restrict__ w1F)
{
    int idx = blockIdx.x * 256 + threadIdx.x;      // 147456
    int e  = idx & 7;
    int t1 = idx >> 3;  int l  = t1 & 63;
    int t2 = t1 >> 6;   int cb = t2 & 1;
    int t3 = t2 >> 1;   int tap = t3 % 9;
    int t4 = t3 / 9;    int cc = t4 & 3;  int nf = t4 >> 2;
    int oc = nf * 16 + (l & 15);
    int ic = cc * 64 + cb * 32 + (l >> 4) * 8 + e;
    w1F[idx] = f2bf(w1[((size_t)oc * C2 + ic) * 9 + tap]);
}

// w2F[nf5][tap9][cb2][lane64][e8] ; oc=nf*16+(l&15) (>=72 -> 0), ic=cb*32+(l>>4)*8+e
__global__ __launch_bounds__(256) void pack_w2f(
    const float* __restrict__ w2, unsigned short* __restrict__ w2F)
{
    int idx = blockIdx.x * 256 + threadIdx.x;      // 46080
    int e  = idx & 7;
    int t1 = idx >> 3;  int l  = t1 & 63;
    int t2 = t1 >> 6;   int cb = t2 & 1;
    int t3 = t2 >> 1;   int tap = t3 % 9;
    int nf = t3 / 9;
    int oc = nf * 16 + (l & 15);
    int ic = cb * 32 + (l >> 4) * 8 + e;
    float v = (oc < OFFC) ? w2[((size_t)oc * MID + ic) * 9 + tap] : 0.f;
    w2F[idx] = f2bf(v);
}

// dwF[g4][tap9][ocb2][lane64][e8] ; oc_local=ocb*16+(l&15), c=(l>>4)*8+e
__global__ __launch_bounds__(256) void pack_dwf(
    const float* __restrict__ dw, unsigned short* __restrict__ dwF)
{
    int idx = blockIdx.x * 256 + threadIdx.x;      // 36864
    int e   = idx & 7;
    int l   = (idx >> 3) & 63;
    int ocb = (idx >> 9) & 1;
    int gt  = idx >> 10;
    int tap = gt % 9, g = gt / 9;
    int oc = ocb * 16 + (l & 15);
    int c  = (l >> 4) * 8 + e;
    dwF[idx] = f2bf(dw[((size_t)(g * CG + oc) * CG + c) * 9 + tap]);
}

// ---------------- conv1: implicit GEMM, LDS-staged A, fragment-packed B -------
// grid: B*H (b = bid&7 -> XCD-chunked); block 256 = 4 waves (nf = 16 oc each)
__global__ __launch_bounds__(256) void conv1_mfma(
    const unsigned short* __restrict__ rgbcp, const unsigned short* __restrict__ w1F,
    const float* __restrict__ b1, unsigned short* __restrict__ hdnp)
{
    const int by = blockIdx.x;
    const int b = by & 7, y = by >> 3;
    const int tid = threadIdx.x;
    const int nf = tid >> 6;
    const int l = tid & 63, l15 = l & 15, lk = l >> 4;

    __shared__ __align__(16) unsigned short st[3 * 82 * STP];   // 35.4 KB

    f32x4 acc[5];
    #pragma unroll
    for (int i = 0; i < 5; ++i) acc[i] = (f32x4){0.f, 0.f, 0.f, 0.f};

    const size_t rowbase = (size_t)b * PP + (size_t)y * PD;   // padded row y = out row -1

    for (int cc = 0; cc < 4; ++cc) {
        __syncthreads();
        // stage 3 rows x 82 px x 64 ch, dense coalesced 16B units
        for (int e = tid; e < 3 * 82 * 8; e += 256) {
            int r   = e / 656;
            int rem = e - r * 656;
            int px  = rem >> 3;
            int c8  = rem & 7;
            const uint4 v = *(const uint4*)(rgbcp + (rowbase + (size_t)r * PD + px) * C2 + cc * 64 + c8 * 8);
            *(uint4*)&st[(r * 82 + px) * STP + c8 * 8] = v;
        }
        __syncthreads();

        const unsigned short* bw = w1F + (((size_t)(nf * 4 + cc) * 9) * 2 * 64) * 8;
        #pragma unroll
        for (int tap = 0; tap < 9; ++tap) {
            const int ky = tap / 3, kx = tap - ky * 3;
            #pragma unroll
            for (int cb = 0; cb < 2; ++cb) {
                bf16x8 bf = *(const bf16x8*)(bw + ((size_t)(tap * 2 + cb) * 64 + l) * 8);
                #pragma unroll
                for (int mf = 0; mf < 5; ++mf) {
                    bf16x8 af = *(const bf16x8*)&st[(ky * 82 + mf * 16 + l15 + kx) * STP + cb * 32 + lk * 8];
                    acc[mf] = __builtin_amdgcn_mfma_f32_16x16x32_bf16(af, bf, acc[mf], 0, 0, 0);
                }
            }
        }
    }

    const int oc = nf * 16 + l15;
    const float bias = b1[oc];
    unsigned short* ob = hdnp + ((size_t)b * PP + (size_t)(y + 1) * PD + 1) * MID + oc;
    #pragma unroll
    for (int mf = 0; mf < 5; ++mf)
        #pragma unroll
        for (int r = 0; r < 4; ++r) {
            float v = acc[mf][r] + bias;
            v = v > 0.f ? v : 0.f;
            ob[(size_t)(mf * 16 + lk * 4 + r) * MID] = f2bf(v);
        }
}

// ---------------- conv2: implicit GEMM, LDS-staged A, fragment-packed B -------
// grid: B*H (b = bid&7); block 320 = 5 waves (nf = 16 oc of 80 padded)
__global__ __launch_bounds__(320) void conv2_mfma(
    const unsigned short* __restrict__ hdnp, const unsigned short* __restrict__ w2F,
    const float* __restrict__ b2, const float* __restrict__ scale_p,
    float* __restrict__ offs)
{
    const int by = blockIdx.x;
    const int b = by & 7, y = by >> 3;
    const int tid = threadIdx.x;
    const int nf = tid / 64;
    const int l = tid & 63, l15 = l & 15, lk = l >> 4;

    __shared__ __align__(16) unsigned short st[3 * 82 * STP];

    f32x4 acc[5];
    #pragma unroll
    for (int i = 0; i < 5; ++i) acc[i] = (f32x4){0.f, 0.f, 0.f, 0.f};

    const size_t rowbase = (size_t)b * PP + (size_t)y * PD;

    for (int e = tid; e < 3 * 82 * 8; e += 320) {
        int r   = e / 656;
        int rem = e - r * 656;
        int px  = rem >> 3;
        int c8  = rem & 7;
        const uint4 v = *(const uint4*)(hdnp + (rowbase + (size_t)r * PD + px) * MID + c8 * 8);
        *(uint4*)&st[(r * 82 + px) * STP + c8 * 8] = v;
    }
    __syncthreads();

    const unsigned short* bw = w2F + ((size_t)nf * 9 * 2 * 64) * 8;
    #pragma unroll
    for (int tap = 0; tap < 9; ++tap) {
        const int ky = tap / 3, kx = tap - ky * 3;
        #pragma unroll
        for (int cb = 0; cb < 2; ++cb) {
            bf16x8 bf = *(const bf16x8*)(bw + ((size_t)(tap * 2 + cb) * 64 + l) * 8);
            #pragma unroll
            for (int mf = 0; mf < 5; ++mf) {
                bf16x8 af = *(const bf16x8*)&st[(ky * 82 + mf * 16 + l15 + kx) * STP + cb * 32 + lk * 8];
                acc[mf] = __builtin_amdgcn_mfma_f32_16x16x32_bf16(af, bf, acc[mf], 0, 0, 0);
            }
        }
    }

    const int oc = nf * 16 + l15;
    if (oc < OFFC) {
        const float scale = scale_p[0];
        const float bias = b2[oc];
        float* ob = offs + ((size_t)b * OFFC + oc) * HW + y * WW;
        #pragma unroll
        for (int mf = 0; mf < 5; ++mf) {
            float4 v;
            v.x = (acc[mf][0] + bias) * scale;
            v.y = (acc[mf][1] + bias) * scale;
            v.z = (acc[mf][2] + bias) * scale;
            v.w = (acc[mf][3] + bias) * scale;
            *(float4*)(ob + mf * 16 + lk * 4) = v;
        }
    }
}

// ---------------- deformable conv 3x3, groups=4, MFMA channel mix ------------
// block = (ptile, b): 4 waves = 4 groups of the SAME 16 pixels; b = bid&7
__global__ __launch_bounds__(256) void deform_kernel(
    const unsigned short* __restrict__ rgbcp, const float* __restrict__ offs,
    const unsigned short* __restrict__ dwF, const float* __restrict__ db,
    float* __restrict__ out)
{
    const int b = blockIdx.x & 7;
    const int ptile = blockIdx.x >> 3;        // 0..399
    const int g = threadIdx.x >> 6;           // wave = group
    const int l = threadIdx.x & 63, l15 = l & 15, lk = l >> 4;

    const int p0 = ptile * 16;
    const int y  = p0 / WW;            // wave-uniform (80 % 16 == 0)
    const int x  = p0 - y * WW + l15;
    const int p  = p0 + l15;

    f32x4 acc[2];
    acc[0] = (f32x4){0.f, 0.f, 0.f, 0.f};
    acc[1] = (f32x4){0.f, 0.f, 0.f, 0.f};

    const unsigned short* gb = rgbcp + (size_t)b * PP * C2 + g * CG + lk * 8;
    const unsigned short* wg = dwF + (size_t)g * 9 * 2 * 64 * 8;
    const float* ob = offs + ((size_t)b * OFFC + g * 18) * HW + p;

    for (int tap = 0; tap < 9; ++tap) {
        const int ky = tap / 3 - 1;
        const int kx = tap - (tap / 3) * 3 - 1;
        float offy = ob[(size_t)(2 * tap) * HW];
        float offx = ob[(size_t)(2 * tap + 1) * HW];
        float sy = (float)(y + ky) + offy;
        float sx = (float)(x + kx) + offx;
        float fy = floorf(sy), fx = floorf(sx);
        int iy = (int)fy, ix = (int)fx;
        float wy = sy - fy, wx = sx - fx;

        float my0 = ((unsigned)iy       < HH) ? 1.f : 0.f;
        float my1 = ((unsigned)(iy + 1) < HH) ? 1.f : 0.f;
        float mx0 = ((unsigned)ix       < WW) ? 1.f : 0.f;
        float mx1 = ((unsigned)(ix + 1) < WW) ? 1.f : 0.f;
        float w00 = (1.f - wy) * (1.f - wx) * my0 * mx0;
        float w01 = (1.f - wy) * wx         * my0 * mx1;
        float w10 = wy * (1.f - wx)         * my1 * mx0;
        float w11 = wy * wx                 * my1 * mx1;

        int cy0 = min(max(iy, 0), HH - 1) + 1;
        int cy1 = min(max(iy + 1, 0), HH - 1) + 1;
        int cx0 = min(max(ix, 0), WW - 1) + 1;
        int cx1 = min(max(ix + 1, 0), WW - 1) + 1;

        float s[8];
        #pragma unroll
        for (int i = 0; i < 8; ++i) s[i] = 0.f;

        auto corner = [&](int cy, int cx, float wgt) {
            uint4 v = *(const uint4*)(gb + ((size_t)cy * PD + cx) * C2);
            unsigned u[4] = {v.x, v.y, v.z, v.w};
            #pragma unroll
            for (int j = 0; j < 4; ++j) {
                float f0 = __uint_as_float(u[j] << 16);
                float f1 = __uint_as_float(u[j] & 0xffff0000u);
                s[2 * j]     = fmaf(f0, wgt, s[2 * j]);
                s[2 * j + 1] = fmaf(f1, wgt, s[2 * j + 1]);
            }
        };
        corner(cy0, cx0, w00);
        corner(cy0, cx1, w01);
        corner(cy1, cx0, w10);
        corner(cy1, cx1, w11);

        union { bf16x8 v; unsigned u[4]; } af;
        #pragma unroll
        for (int j = 0; j < 4; ++j)
            asm volatile("v_cvt_pk_bf16_f32 %0, %1, %2"
                         : "=v"(af.u[j]) : "v"(s[2 * j]), "v"(s[2 * j + 1]));

        const unsigned short* wt = wg + (size_t)tap * 2 * 64 * 8;
        bf16x8 bf0 = *(const bf16x8*)(wt + (size_t)l * 8);
        bf16x8 bf1 = *(const bf16x8*)(wt + ((size_t)64 + l) * 8);
        acc[0] = __builtin_amdgcn_mfma_f32_16x16x32_bf16(af.v, bf0, acc[0], 0, 0, 0);
        acc[1] = __builtin_amdgcn_mfma_f32_16x16x32_bf16(af.v, bf1, acc[1], 0, 0, 0);
    }

    #pragma unroll
    for (int ocb = 0; ocb < 2; ++ocb) {
        const int oc = g * CG + ocb * 16 + l15;
        const float bias = db[oc];
        float4 v;
        v.x = acc[ocb][0] + bias;
        v.y = acc[ocb][1] + bias;
        v.z = acc[ocb][2] + bias;
        v.w = acc[ocb][3] + bias;
        *(float4*)(out + ((size_t)b * CIN + oc) * HW + p0 + lk * 4) = v;
    }
}

extern "C" void kernel_launch(void* const* d_in, const int* in_sizes, int n_in,
                              void* d_out, int out_size, void* d_ws, size_t ws_size,
                              hipStream_t stream) {
    const float* rgb     = (const float*)d_in[0];
    const float* thermal = (const float*)d_in[1];
    const float* w1      = (const float*)d_in[2];
    const float* b1      = (const float*)d_in[3];
    const float* w2      = (const float*)d_in[4];
    const float* b2      = (const float*)d_in[5];
    const float* dw      = (const float*)d_in[6];
    const float* db      = (const float*)d_in[7];
    const float* osc     = (const float*)d_in[8];

    char* w = (char*)d_ws;
    unsigned short* rgbcp = (unsigned short*)w;  w += (size_t)BB * PP * C2 * 2;
    unsigned short* hdnp  = (unsigned short*)w;  w += (size_t)BB * PP * MID * 2;
    float*          offs  = (float*)w;           w += (size_t)BB * OFFC * HW * 4;
    unsigned short* w1F   = (unsigned short*)w;  w += (size_t)4 * 4 * 9 * 2 * 64 * 8 * 2;
    unsigned short* w2F   = (unsigned short*)w;  w += (size_t)5 * 9 * 2 * 64 * 8 * 2;
    unsigned short* dwF   = (unsigned short*)w;  w += (size_t)4 * 9 * 2 * 64 * 8 * 2;
    float* out = (float*)d_out;

    zero_borders<<<dim3((BB * 324 + 255) / 256), 256, 0, stream>>>(rgbcp, hdnp);
    pack_rgbc<<<dim3(BB * HH * 8), 256, 0, stream>>>(rgb, thermal, rgbcp);
    pack_w1f<<<dim3(147456 / 256), 256, 0, stream>>>(w1, w1F);
    pack_w2f<<<dim3(46080 / 256), 256, 0, stream>>>(w2, w2F);
    pack_dwf<<<dim3(36864 / 256), 256, 0, stream>>>(dw, dwF);
    conv1_mfma<<<dim3(BB * HH), 256, 0, stream>>>(rgbcp, w1F, b1, hdnp);
    conv2_mfma<<<dim3(BB * HH), 320, 0, stream>>>(hdnp, w2F, b2, osc, offs);
    deform_kernel<<<dim3(BB * NG * 400 / 4), 256, 0, stream>>>(rgbcp, offs, dwF, db, out);
}

// Round 8
// 132.599 us; speedup vs baseline: 2.3351x; 1.0042x over previous
//
#include <hip/hip_runtime.h>

#define HH 80
#define WW 80
#define BB 8
#define CIN 128
#define C2 256
#define MID 64
#define OFFC 72
#define NG 4
#define CG 32
#define HW (HH * WW)
#define PD 82           // padded spatial dim
#define PP (PD * PD)    // padded pixels per image
#define STP 72          // LDS px stride in channels (144B, 16B-aligned, even banks)

typedef short bf16x8 __attribute__((ext_vector_type(8)));
typedef float f32x4  __attribute__((ext_vector_type(4)));

static __device__ __forceinline__ unsigned short f2bf(float f) {
    union { float f; unsigned u; } v; v.f = f;
    unsigned r = v.u + 0x7fffu + ((v.u >> 16) & 1u);   // RNE
    return (unsigned short)(r >> 16);
}

// ---------------- zero the 1-px border of padded bf16 buffers (every call) ----
__global__ __launch_bounds__(256) void zero_borders(
    unsigned short* __restrict__ rgbcp, unsigned short* __restrict__ hdnp)
{
    int idx = blockIdx.x * 256 + threadIdx.x;
    if (idx >= BB * 324) return;
    int b = idx / 324, e = idx - (idx / 324) * 324;
    int y, x;
    if (e < 82)       { y = 0;  x = e; }
    else if (e < 164) { y = 81; x = e - 82; }
    else if (e < 244) { y = e - 164 + 1; x = 0; }
    else              { y = e - 244 + 1; x = 81; }
    size_t pos = (size_t)b * PP + y * PD + x;
    uint4 z = {0, 0, 0, 0};
    uint4* r = (uint4*)(rgbcp + pos * C2);
    #pragma unroll
    for (int i = 0; i < 32; ++i) r[i] = z;
    uint4* h = (uint4*)(hdnp + pos * MID);
    #pragma unroll
    for (int i = 0; i < 8; ++i) h[i] = z;
}

// ---------------- pack concat(rgb,thermal) NCHW fp32 -> padded NHWC bf16 ------
__global__ __launch_bounds__(256) void pack_rgbc(
    const float* __restrict__ rgb, const float* __restrict__ thermal,
    unsigned short* __restrict__ rgbcp)
{
    const int bid = blockIdx.x;
    const int ct  = bid & 7;
    const int rem = bid >> 3;
    const int y = rem % HH, b = rem / HH;
    const float* src = (ct < 4) ? rgb : thermal;
    const int cbase = (ct & 3) * 32;

    __shared__ float tile[32][81];
    for (int e = threadIdx.x; e < 32 * WW; e += 256) {
        int c = e / WW, x = e - c * WW;
        tile[c][x] = src[((size_t)(b * CIN + cbase + c) * HH + y) * WW + x];
    }
    __syncthreads();
    for (int e = threadIdx.x; e < 16 * WW; e += 256) {
        int x = e >> 4, cp = (e & 15) * 2;
        unsigned lo = f2bf(tile[cp][x]);
        unsigned hi = f2bf(tile[cp + 1][x]);
        *(unsigned*)(rgbcp + ((size_t)b * PP + (size_t)(y + 1) * PD + x + 1) * C2 + ct * 32 + cp)
            = lo | (hi << 16);
    }
}

// ---------------- weight packs into MFMA fragment order ----------------
// w1F[nf4][cc4][tap9][cb2][lane64][e8] ; oc=nf*16+(l&15), ic=cc*64+cb*32+(l>>4)*8+e
__global__ __launch_bounds__(256) void pack_w1f(
    const float* __restrict__ w1, unsigned short* __restrict__ w1F)
{
    int idx = blockIdx.x * 256 + threadIdx.x;      // 147456
    int e  = idx & 7;
    int t1 = idx >> 3;  int l  = t1 & 63;
    int t2 = t1 >> 6;   int cb = t2 & 1;
    int t3 = t2 >> 1;   int tap = t3 % 9;
    int t4 = t3 / 9;    int cc = t4 & 3;  int nf = t4 >> 2;
    int oc = nf * 16 + (l & 15);
    int ic = cc * 64 + cb * 32 + (l >> 4) * 8 + e;
    w1F[idx] = f2bf(w1[((size_t)oc * C2 + ic) * 9 + tap]);
}

// w2F[nf5][tap9][cb2][lane64][e8] ; oc=nf*16+(l&15) (>=72 -> 0), ic=cb*32+(l>>4)*8+e
__global__ __launch_bounds__(256) void pack_w2f(
    const float* __restrict__ w2, unsigned short* __restrict__ w2F)
{
    int idx = blockIdx.x * 256 + threadIdx.x;      // 46080
    int e  = idx & 7;
    int t1 = idx >> 3;  int l  = t1 & 63;
    int t2 = t1 >> 6;   int cb = t2 & 1;
    int t3 = t2 >> 1;   int tap = t3 % 9;
    int nf = t3 / 9;
    int oc = nf * 16 + (l & 15);
    int ic = cb * 32 + (l >> 4) * 8 + e;
    float v = (oc < OFFC) ? w2[((size_t)oc * MID + ic) * 9 + tap] : 0.f;
    w2F[idx] = f2bf(v);
}

// dwF[g4][tap9][ocb2][lane64][e8] ; oc_local=ocb*16+(l&15), c=(l>>4)*8+e
__global__ __launch_bounds__(256) void pack_dwf(
    const float* __restrict__ dw, unsigned short* __restrict__ dwF)
{
    int idx = blockIdx.x * 256 + threadIdx.x;      // 36864
    int e   = idx & 7;
    int l   = (idx >> 3) & 63;
    int ocb = (idx >> 9) & 1;
    int gt  = idx >> 10;
    int tap = gt % 9, g = gt / 9;
    int oc = ocb * 16 + (l & 15);
    int c  = (l >> 4) * 8 + e;
    dwF[idx] = f2bf(dw[((size_t)(g * CG + oc) * CG + c) * 9 + tap]);
}

// ---------------- conv1: implicit GEMM, LDS-staged A, fragment-packed B -------
// grid: B*H (b = bid&7 -> XCD-chunked); block 256 = 4 waves (nf = 16 oc each)
__global__ __launch_bounds__(256) void conv1_mfma(
    const unsigned short* __restrict__ rgbcp, const unsigned short* __restrict__ w1F,
    const float* __restrict__ b1, unsigned short* __restrict__ hdnp)
{
    const int by = blockIdx.x;
    const int b = by & 7, y = by >> 3;
    const int tid = threadIdx.x;
    const int nf = tid >> 6;
    const int l = tid & 63, l15 = l & 15, lk = l >> 4;

    __shared__ __align__(16) unsigned short st[3 * 82 * STP];   // 35.4 KB

    f32x4 acc[5];
    #pragma unroll
    for (int i = 0; i < 5; ++i) acc[i] = (f32x4){0.f, 0.f, 0.f, 0.f};

    const size_t rowbase = (size_t)b * PP + (size_t)y * PD;   // padded row y = out row -1

    for (int cc = 0; cc < 4; ++cc) {
        __syncthreads();
        // stage 3 rows x 82 px x 64 ch, dense coalesced 16B units
        for (int e = tid; e < 3 * 82 * 8; e += 256) {
            int r   = e / 656;
            int rem = e - r * 656;
            int px  = rem >> 3;
            int c8  = rem & 7;
            const uint4 v = *(const uint4*)(rgbcp + (rowbase + (size_t)r * PD + px) * C2 + cc * 64 + c8 * 8);
            *(uint4*)&st[(r * 82 + px) * STP + c8 * 8] = v;
        }
        __syncthreads();

        const unsigned short* bw = w1F + (((size_t)(nf * 4 + cc) * 9) * 2 * 64) * 8;
        #pragma unroll
        for (int tap = 0; tap < 9; ++tap) {
            const int ky = tap / 3, kx = tap - ky * 3;
            #pragma unroll
            for (int cb = 0; cb < 2; ++cb) {
                bf16x8 bf = *(const bf16x8*)(bw + ((size_t)(tap * 2 + cb) * 64 + l) * 8);
                #pragma unroll
                for (int mf = 0; mf < 5; ++mf) {
                    bf16x8 af = *(const bf16x8*)&st[(ky * 82 + mf * 16 + l15 + kx) * STP + cb * 32 + lk * 8];
                    acc[mf] = __builtin_amdgcn_mfma_f32_16x16x32_bf16(af, bf, acc[mf], 0, 0, 0);
                }
            }
        }
    }

    const int oc = nf * 16 + l15;
    const float bias = b1[oc];
    unsigned short* ob = hdnp + ((size_t)b * PP + (size_t)(y + 1) * PD + 1) * MID + oc;
    #pragma unroll
    for (int mf = 0; mf < 5; ++mf)
        #pragma unroll
        for (int r = 0; r < 4; ++r) {
            float v = acc[mf][r] + bias;
            v = v > 0.f ? v : 0.f;
            ob[(size_t)(mf * 16 + lk * 4 + r) * MID] = f2bf(v);
        }
}

// ---------------- conv2: implicit GEMM, LDS-staged A, fragment-packed B -------
// grid: B*H (b = bid&7); block 320 = 5 waves (nf = 16 oc of 80 padded)
__global__ __launch_bounds__(320) void conv2_mfma(
    const unsigned short* __restrict__ hdnp, const unsigned short* __restrict__ w2F,
    const float* __restrict__ b2, const float* __restrict__ scale_p,
    float* __restrict__ offs)
{
    const int by = blockIdx.x;
    const int b = by & 7, y = by >> 3;
    const int tid = threadIdx.x;
    const int nf = tid / 64;
    const int l = tid & 63, l15 = l & 15, lk = l >> 4;

    __shared__ __align__(16) unsigned short st[3 * 82 * STP];

    f32x4 acc[5];
    #pragma unroll
    for (int i = 0; i < 5; ++i) acc[i] = (f32x4){0.f, 0.f, 0.f, 0.f};

    const size_t rowbase = (size_t)b * PP + (size_t)y * PD;

    for (int e = tid; e < 3 * 82 * 8; e += 320) {
        int r   = e / 656;
        int rem = e - r * 656;
        int px  = rem >> 3;
        int c8  = rem & 7;
        const uint4 v = *(const uint4*)(hdnp + (rowbase + (size_t)r * PD + px) * MID + c8 * 8);
        *(uint4*)&st[(r * 82 + px) * STP + c8 * 8] = v;
    }
    __syncthreads();

    const unsigned short* bw = w2F + ((size_t)nf * 9 * 2 * 64) * 8;
    #pragma unroll
    for (int tap = 0; tap < 9; ++tap) {
        const int ky = tap / 3, kx = tap - ky * 3;
        #pragma unroll
        for (int cb = 0; cb < 2; ++cb) {
            bf16x8 bf = *(const bf16x8*)(bw + ((size_t)(tap * 2 + cb) * 64 + l) * 8);
            #pragma unroll
            for (int mf = 0; mf < 5; ++mf) {
                bf16x8 af = *(const bf16x8*)&st[(ky * 82 + mf * 16 + l15 + kx) * STP + cb * 32 + lk * 8];
                acc[mf] = __builtin_amdgcn_mfma_f32_16x16x32_bf16(af, bf, acc[mf], 0, 0, 0);
            }
        }
    }

    const int oc = nf * 16 + l15;
    if (oc < OFFC) {
        const float scale = scale_p[0];
        const float bias = b2[oc];
        float* ob = offs + ((size_t)b * OFFC + oc) * HW + y * WW;
        #pragma unroll
        for (int mf = 0; mf < 5; ++mf) {
            float4 v;
            v.x = (acc[mf][0] + bias) * scale;
            v.y = (acc[mf][1] + bias) * scale;
            v.z = (acc[mf][2] + bias) * scale;
            v.w = (acc[mf][3] + bias) * scale;
            *(float4*)(ob + mf * 16 + lk * 4) = v;
        }
    }
}

// ---------------- deformable conv 3x3, groups=4, MFMA mix, pipelined gathers --
// block = (ptile, b): 4 waves = 4 groups of the SAME 16 pixels; b = bid&7
__global__ __launch_bounds__(256) void deform_kernel(
    const unsigned short* __restrict__ rgbcp, const float* __restrict__ offs,
    const unsigned short* __restrict__ dwF, const float* __restrict__ db,
    float* __restrict__ out)
{
    const int b = blockIdx.x & 7;
    const int ptile = blockIdx.x >> 3;        // 0..399
    const int g = threadIdx.x >> 6;           // wave = group
    const int l = threadIdx.x & 63, l15 = l & 15, lk = l >> 4;

    const int p0 = ptile * 16;
    const int y  = p0 / WW;            // wave-uniform (80 % 16 == 0)
    const int x  = p0 - y * WW + l15;
    const int p  = p0 + l15;

    f32x4 acc0 = (f32x4){0.f, 0.f, 0.f, 0.f};
    f32x4 acc1 = (f32x4){0.f, 0.f, 0.f, 0.f};

    const unsigned short* gb = rgbcp + (size_t)b * PP * C2 + g * CG + lk * 8;
    const unsigned short* wg = dwF + (size_t)g * 9 * 2 * 64 * 8 + (size_t)l * 8;
    const float* ob = offs + ((size_t)b * OFFC + g * 18) * HW + p;

    // 1) all 18 offset loads up front; sample coords in regs
    float sy[9], sx[9];
    #pragma unroll
    for (int t = 0; t < 9; ++t) {
        float offy = ob[(size_t)(2 * t) * HW];
        float offx = ob[(size_t)(2 * t + 1) * HW];
        sy[t] = (float)(y + t / 3 - 1) + offy;
        sx[t] = (float)(x + t % 3 - 1) + offx;
    }

    // 2) depth-2 software pipeline over taps (all indices static after unroll)
    uint4 gr[3][4];
    float wq[3][4];

#define ISSUE(t, s) { \
        float fy = floorf(sy[t]), fx = floorf(sx[t]); \
        int iy = (int)fy, ix = (int)fx; \
        float wy = sy[t] - fy, wx = sx[t] - fx; \
        float my0 = ((unsigned)iy       < HH) ? 1.f : 0.f; \
        float my1 = ((unsigned)(iy + 1) < HH) ? 1.f : 0.f; \
        float mx0 = ((unsigned)ix       < WW) ? 1.f : 0.f; \
        float mx1 = ((unsigned)(ix + 1) < WW) ? 1.f : 0.f; \
        wq[s][0] = (1.f - wy) * (1.f - wx) * my0 * mx0; \
        wq[s][1] = (1.f - wy) * wx         * my0 * mx1; \
        wq[s][2] = wy * (1.f - wx)         * my1 * mx0; \
        wq[s][3] = wy * wx                 * my1 * mx1; \
        int cy0 = min(max(iy, 0), HH - 1) + 1; \
        int cy1 = min(max(iy + 1, 0), HH - 1) + 1; \
        int cx0 = min(max(ix, 0), WW - 1) + 1; \
        int cx1 = min(max(ix + 1, 0), WW - 1) + 1; \
        gr[s][0] = *(const uint4*)(gb + ((size_t)cy0 * PD + cx0) * C2); \
        gr[s][1] = *(const uint4*)(gb + ((size_t)cy0 * PD + cx1) * C2); \
        gr[s][2] = *(const uint4*)(gb + ((size_t)cy1 * PD + cx0) * C2); \
        gr[s][3] = *(const uint4*)(gb + ((size_t)cy1 * PD + cx1) * C2); \
    }

    ISSUE(0, 0)
    ISSUE(1, 1)

    #pragma unroll
    for (int t = 0; t < 9; ++t) {
        if (t < 7) ISSUE(t + 2, (t + 2) % 3)

        const int cur = t % 3;
        float sm[8];
        #pragma unroll
        for (int i = 0; i < 8; ++i) sm[i] = 0.f;
        #pragma unroll
        for (int c = 0; c < 4; ++c) {
            float wgt = wq[cur][c];
            unsigned uu[4] = {gr[cur][c].x, gr[cur][c].y, gr[cur][c].z, gr[cur][c].w};
            #pragma unroll
            for (int j = 0; j < 4; ++j) {
                float f0 = __uint_as_float(uu[j] << 16);
                float f1 = __uint_as_float(uu[j] & 0xffff0000u);
                sm[2 * j]     = fmaf(f0, wgt, sm[2 * j]);
                sm[2 * j + 1] = fmaf(f1, wgt, sm[2 * j + 1]);
            }
        }

        union { bf16x8 v; unsigned u[4]; } af;
        #pragma unroll
        for (int j = 0; j < 4; ++j)
            asm volatile("v_cvt_pk_bf16_f32 %0, %1, %2"
                         : "=v"(af.u[j]) : "v"(sm[2 * j]), "v"(sm[2 * j + 1]));

        bf16x8 bf0 = *(const bf16x8*)(wg + (size_t)t * 2 * 64 * 8);
        bf16x8 bf1 = *(const bf16x8*)(wg + (size_t)t * 2 * 64 * 8 + 64 * 8);
        acc0 = __builtin_amdgcn_mfma_f32_16x16x32_bf16(af.v, bf0, acc0, 0, 0, 0);
        acc1 = __builtin_amdgcn_mfma_f32_16x16x32_bf16(af.v, bf1, acc1, 0, 0, 0);
    }
#undef ISSUE

    {
        const int oc = g * CG + l15;
        const float bias = db[oc];
        float4 v;
        v.x = acc0[0] + bias; v.y = acc0[1] + bias;
        v.z = acc0[2] + bias; v.w = acc0[3] + bias;
        *(float4*)(out + ((size_t)b * CIN + oc) * HW + p0 + lk * 4) = v;
    }
    {
        const int oc = g * CG + 16 + l15;
        const float bias = db[oc];
        float4 v;
        v.x = acc1[0] + bias; v.y = acc1[1] + bias;
        v.z = acc1[2] + bias; v.w = acc1[3] + bias;
        *(float4*)(out + ((size_t)b * CIN + oc) * HW + p0 + lk * 4) = v;
    }
}

extern "C" void kernel_launch(void* const* d_in, const int* in_sizes, int n_in,
                              void* d_out, int out_size, void* d_ws, size_t ws_size,
                              hipStream_t stream) {
    const float* rgb     = (const float*)d_in[0];
    const float* thermal = (const float*)d_in[1];
    const float* w1      = (const float*)d_in[2];
    const float* b1      = (const float*)d_in[3];
    const float* w2      = (const float*)d_in[4];
    const float* b2      = (const float*)d_in[5];
    const float* dw      = (const float*)d_in[6];
    const float* db      = (const float*)d_in[7];
    const float* osc     = (const float*)d_in[8];

    char* w = (char*)d_ws;
    unsigned short* rgbcp = (unsigned short*)w;  w += (size_t)BB * PP * C2 * 2;
    unsigned short* hdnp  = (unsigned short*)w;  w += (size_t)BB * PP * MID * 2;
    float*          offs  = (float*)w;           w += (size_t)BB * OFFC * HW * 4;
    unsigned short* w1F   = (unsigned short*)w;  w += (size_t)4 * 4 * 9 * 2 * 64 * 8 * 2;
    unsigned short* w2F   = (unsigned short*)w;  w += (size_t)5 * 9 * 2 * 64 * 8 * 2;
    unsigned short* dwF   = (unsigned short*)w;  w += (size_t)4 * 9 * 2 * 64 * 8 * 2;
    float* out = (float*)d_out;

    zero_borders<<<dim3((BB * 324 + 255) / 256), 256, 0, stream>>>(rgbcp, hdnp);
    pack_rgbc<<<dim3(BB * HH * 8), 256, 0, stream>>>(rgb, thermal, rgbcp);
    pack_w1f<<<dim3(147456 / 256), 256, 0, stream>>>(w1, w1F);
    pack_w2f<<<dim3(46080 / 256), 256, 0, stream>>>(w2, w2F);
    pack_dwf<<<dim3(36864 / 256), 256, 0, stream>>>(dw, dwF);
    conv1_mfma<<<dim3(BB * HH), 256, 0, stream>>>(rgbcp, w1F, b1, hdnp);
    conv2_mfma<<<dim3(BB * HH), 320, 0, stream>>>(hdnp, w2F, b2, osc, offs);
    deform_kernel<<<dim3(BB * NG * 400 / 4), 256, 0, stream>>>(rgbcp, offs, dwF, db, out);
}

// Round 9
// 109.997 us; speedup vs baseline: 2.8149x; 1.2055x over previous
//
#include <hip/hip_runtime.h>

#define HH 80
#define WW 80
#define BB 8
#define CIN 128
#define C2 256
#define MID 64
#define OFFC 72
#define NG 4
#define CG 32
#define HW (HH * WW)
#define PD 82           // padded spatial dim
#define PP (PD * PD)    // padded pixels per image
#define STP 72          // conv LDS px stride in channels
#define DSTP 40         // deform LDS px stride in shorts (80 B)

typedef short bf16x8 __attribute__((ext_vector_type(8)));
typedef float f32x4  __attribute__((ext_vector_type(4)));

static __device__ __forceinline__ unsigned short f2bf(float f) {
    union { float f; unsigned u; } v; v.f = f;
    unsigned r = v.u + 0x7fffu + ((v.u >> 16) & 1u);   // RNE
    return (unsigned short)(r >> 16);
}

// ---------------- zero the 1-px border of padded bf16 buffers (every call) ----
__global__ __launch_bounds__(256) void zero_borders(
    unsigned short* __restrict__ rgbcp, unsigned short* __restrict__ hdnp)
{
    int idx = blockIdx.x * 256 + threadIdx.x;
    if (idx >= BB * 324) return;
    int b = idx / 324, e = idx - (idx / 324) * 324;
    int y, x;
    if (e < 82)       { y = 0;  x = e; }
    else if (e < 164) { y = 81; x = e - 82; }
    else if (e < 244) { y = e - 164 + 1; x = 0; }
    else              { y = e - 244 + 1; x = 81; }
    size_t pos = (size_t)b * PP + y * PD + x;
    uint4 z = {0, 0, 0, 0};
    uint4* r = (uint4*)(rgbcp + pos * C2);
    #pragma unroll
    for (int i = 0; i < 32; ++i) r[i] = z;
    uint4* h = (uint4*)(hdnp + pos * MID);
    #pragma unroll
    for (int i = 0; i < 8; ++i) h[i] = z;
}

// ---------------- pack concat(rgb,thermal) NCHW fp32 -> padded NHWC bf16 ------
__global__ __launch_bounds__(256) void pack_rgbc(
    const float* __restrict__ rgb, const float* __restrict__ thermal,
    unsigned short* __restrict__ rgbcp)
{
    const int bid = blockIdx.x;
    const int ct  = bid & 7;
    const int rem = bid >> 3;
    const int y = rem % HH, b = rem / HH;
    const float* src = (ct < 4) ? rgb : thermal;
    const int cbase = (ct & 3) * 32;

    __shared__ float tile[32][81];
    for (int e = threadIdx.x; e < 32 * WW; e += 256) {
        int c = e / WW, x = e - c * WW;
        tile[c][x] = src[((size_t)(b * CIN + cbase + c) * HH + y) * WW + x];
    }
    __syncthreads();
    for (int e = threadIdx.x; e < 16 * WW; e += 256) {
        int x = e >> 4, cp = (e & 15) * 2;
        unsigned lo = f2bf(tile[cp][x]);
        unsigned hi = f2bf(tile[cp + 1][x]);
        *(unsigned*)(rgbcp + ((size_t)b * PP + (size_t)(y + 1) * PD + x + 1) * C2 + ct * 32 + cp)
            = lo | (hi << 16);
    }
}

// ---------------- merged weight packs into MFMA fragment order ----------------
// [0,147456): w1F[nf4][cc4][tap9][cb2][lane64][e8]
// [147456,193536): w2F[nf5][tap9][cb2][lane64][e8]
// [193536,230400): dwF[g4][tap9][ocb2][lane64][e8]
__global__ __launch_bounds__(256) void pack_weights(
    const float* __restrict__ w1, const float* __restrict__ w2,
    const float* __restrict__ dw,
    unsigned short* __restrict__ w1F, unsigned short* __restrict__ w2F,
    unsigned short* __restrict__ dwF)
{
    int idx = blockIdx.x * 256 + threadIdx.x;
    if (idx < 147456) {
        int e  = idx & 7;
        int t1 = idx >> 3;  int l  = t1 & 63;
        int t2 = t1 >> 6;   int cb = t2 & 1;
        int t3 = t2 >> 1;   int tap = t3 % 9;
        int t4 = t3 / 9;    int cc = t4 & 3;  int nf = t4 >> 2;
        int oc = nf * 16 + (l & 15);
        int ic = cc * 64 + cb * 32 + (l >> 4) * 8 + e;
        w1F[idx] = f2bf(w1[((size_t)oc * C2 + ic) * 9 + tap]);
    } else if (idx < 193536) {
        int i2 = idx - 147456;
        int e  = i2 & 7;
        int t1 = i2 >> 3;  int l  = t1 & 63;
        int t2 = t1 >> 6;  int cb = t2 & 1;
        int t3 = t2 >> 1;  int tap = t3 % 9;
        int nf = t3 / 9;
        int oc = nf * 16 + (l & 15);
        int ic = cb * 32 + (l >> 4) * 8 + e;
        float v = (oc < OFFC) ? w2[((size_t)oc * MID + ic) * 9 + tap] : 0.f;
        w2F[i2] = f2bf(v);
    } else {
        int i3 = idx - 193536;
        int e   = i3 & 7;
        int l   = (i3 >> 3) & 63;
        int ocb = (i3 >> 9) & 1;
        int gt  = i3 >> 10;
        int tap = gt % 9, g = gt / 9;
        int oc = ocb * 16 + (l & 15);
        int c  = (l >> 4) * 8 + e;
        dwF[i3] = f2bf(dw[((size_t)(g * CG + oc) * CG + c) * 9 + tap]);
    }
}

// ---------------- conv1: implicit GEMM, LDS-staged A, fragment-packed B -------
// grid: B*H (b = bid&7 -> XCD-chunked); block 256 = 4 waves (nf = 16 oc each)
__global__ __launch_bounds__(256) void conv1_mfma(
    const unsigned short* __restrict__ rgbcp, const unsigned short* __restrict__ w1F,
    const float* __restrict__ b1, unsigned short* __restrict__ hdnp)
{
    const int by = blockIdx.x;
    const int b = by & 7, y = by >> 3;
    const int tid = threadIdx.x;
    const int nf = tid >> 6;
    const int l = tid & 63, l15 = l & 15, lk = l >> 4;

    __shared__ __align__(16) unsigned short st[3 * 82 * STP];   // 35.4 KB

    f32x4 acc[5];
    #pragma unroll
    for (int i = 0; i < 5; ++i) acc[i] = (f32x4){0.f, 0.f, 0.f, 0.f};

    const size_t rowbase = (size_t)b * PP + (size_t)y * PD;   // padded row y = out row -1

    for (int cc = 0; cc < 4; ++cc) {
        __syncthreads();
        for (int e = tid; e < 3 * 82 * 8; e += 256) {
            int r   = e / 656;
            int rem = e - r * 656;
            int px  = rem >> 3;
            int c8  = rem & 7;
            const uint4 v = *(const uint4*)(rgbcp + (rowbase + (size_t)r * PD + px) * C2 + cc * 64 + c8 * 8);
            *(uint4*)&st[(r * 82 + px) * STP + c8 * 8] = v;
        }
        __syncthreads();

        const unsigned short* bw = w1F + (((size_t)(nf * 4 + cc) * 9) * 2 * 64) * 8;
        #pragma unroll
        for (int tap = 0; tap < 9; ++tap) {
            const int ky = tap / 3, kx = tap - ky * 3;
            #pragma unroll
            for (int cb = 0; cb < 2; ++cb) {
                bf16x8 bf = *(const bf16x8*)(bw + ((size_t)(tap * 2 + cb) * 64 + l) * 8);
                #pragma unroll
                for (int mf = 0; mf < 5; ++mf) {
                    bf16x8 af = *(const bf16x8*)&st[(ky * 82 + mf * 16 + l15 + kx) * STP + cb * 32 + lk * 8];
                    acc[mf] = __builtin_amdgcn_mfma_f32_16x16x32_bf16(af, bf, acc[mf], 0, 0, 0);
                }
            }
        }
    }

    const int oc = nf * 16 + l15;
    const float bias = b1[oc];
    unsigned short* ob = hdnp + ((size_t)b * PP + (size_t)(y + 1) * PD + 1) * MID + oc;
    #pragma unroll
    for (int mf = 0; mf < 5; ++mf)
        #pragma unroll
        for (int r = 0; r < 4; ++r) {
            float v = acc[mf][r] + bias;
            v = v > 0.f ? v : 0.f;
            ob[(size_t)(mf * 16 + lk * 4 + r) * MID] = f2bf(v);
        }
}

// ---------------- conv2: implicit GEMM, LDS-staged A, fragment-packed B -------
// grid: B*H (b = bid&7); block 320 = 5 waves (nf = 16 oc of 80 padded)
__global__ __launch_bounds__(320) void conv2_mfma(
    const unsigned short* __restrict__ hdnp, const unsigned short* __restrict__ w2F,
    const float* __restrict__ b2, const float* __restrict__ scale_p,
    float* __restrict__ offs)
{
    const int by = blockIdx.x;
    const int b = by & 7, y = by >> 3;
    const int tid = threadIdx.x;
    const int nf = tid / 64;
    const int l = tid & 63, l15 = l & 15, lk = l >> 4;

    __shared__ __align__(16) unsigned short st[3 * 82 * STP];

    f32x4 acc[5];
    #pragma unroll
    for (int i = 0; i < 5; ++i) acc[i] = (f32x4){0.f, 0.f, 0.f, 0.f};

    const size_t rowbase = (size_t)b * PP + (size_t)y * PD;

    for (int e = tid; e < 3 * 82 * 8; e += 320) {
        int r   = e / 656;
        int rem = e - r * 656;
        int px  = rem >> 3;
        int c8  = rem & 7;
        const uint4 v = *(const uint4*)(hdnp + (rowbase + (size_t)r * PD + px) * MID + c8 * 8);
        *(uint4*)&st[(r * 82 + px) * STP + c8 * 8] = v;
    }
    __syncthreads();

    const unsigned short* bw = w2F + ((size_t)nf * 9 * 2 * 64) * 8;
    #pragma unroll
    for (int tap = 0; tap < 9; ++tap) {
        const int ky = tap / 3, kx = tap - ky * 3;
        #pragma unroll
        for (int cb = 0; cb < 2; ++cb) {
            bf16x8 bf = *(const bf16x8*)(bw + ((size_t)(tap * 2 + cb) * 64 + l) * 8);
            #pragma unroll
            for (int mf = 0; mf < 5; ++mf) {
                bf16x8 af = *(const bf16x8*)&st[(ky * 82 + mf * 16 + l15 + kx) * STP + cb * 32 + lk * 8];
                acc[mf] = __builtin_amdgcn_mfma_f32_16x16x32_bf16(af, bf, acc[mf], 0, 0, 0);
            }
        }
    }

    const int oc = nf * 16 + l15;
    if (oc < OFFC) {
        const float scale = scale_p[0];
        const float bias = b2[oc];
        float* ob = offs + ((size_t)b * OFFC + oc) * HW + y * WW;
        #pragma unroll
        for (int mf = 0; mf < 5; ++mf) {
            float4 v;
            v.x = (acc[mf][0] + bias) * scale;
            v.y = (acc[mf][1] + bias) * scale;
            v.z = (acc[mf][2] + bias) * scale;
            v.w = (acc[mf][3] + bias) * scale;
            *(float4*)(ob + mf * 16 + lk * 4) = v;
        }
    }
}

// ---------------- deformable conv 3x3: LDS-staged row window + MFMA mix -------
// block = (b, y, g): 320 thr = 5 waves x 16 px of row y, one group.
// Stage padded rows r0..r0+4 (group channel slice); gathers hit LDS; per-lane
// global fallback only when |offset| >= ~1 (never on this data).
__global__ __launch_bounds__(320, 4) void deform_kernel(
    const unsigned short* __restrict__ rgbcp, const float* __restrict__ offs,
    const unsigned short* __restrict__ dwF, const float* __restrict__ db,
    float* __restrict__ out)
{
    const int b = blockIdx.x & 7;
    const int rem = blockIdx.x >> 3;      // 0..319  (y inner, g outer)
    const int y = rem % HH;
    const int g = rem / HH;
    const int wv = threadIdx.x >> 6;      // 0..4
    const int l = threadIdx.x & 63, l15 = l & 15, lk = l >> 4;

    const int x = wv * 16 + l15;
    const int p = y * WW + x;
    const int p0 = y * WW + wv * 16;
    const int r0 = min(max(y - 1, 0), PD - 5);    // staged padded rows r0..r0+4

    __shared__ __align__(16) unsigned short st[5 * 82 * DSTP];   // 32.8 KB

    // ---- stage: 5 rows x 82 px x 32 ch (64 B/px slice) ----
    const unsigned short* gsrc = rgbcp + ((size_t)b * PP + (size_t)r0 * PD) * C2 + g * CG;
    for (int e = threadIdx.x; e < 5 * 82 * 4; e += 320) {
        int r  = e / 328;
        int rm = e - r * 328;
        int px = rm >> 2, c8 = rm & 3;
        uint4 v = *(const uint4*)(gsrc + ((size_t)r * PD + px) * C2 + c8 * 8);
        *(uint4*)&st[(r * 82 + px) * DSTP + c8 * 8] = v;
    }
    __syncthreads();

    // ---- offsets up front ----
    const float* ob = offs + ((size_t)b * OFFC + g * 18) * HW + p;
    float sy[9], sx[9];
    #pragma unroll
    for (int t = 0; t < 9; ++t) {
        float offy = ob[(size_t)(2 * t) * HW];
        float offx = ob[(size_t)(2 * t + 1) * HW];
        sy[t] = (float)(y + t / 3 - 1) + offy;
        sx[t] = (float)(x + t % 3 - 1) + offx;
    }

    f32x4 acc0 = (f32x4){0.f, 0.f, 0.f, 0.f};
    f32x4 acc1 = (f32x4){0.f, 0.f, 0.f, 0.f};
    const unsigned short* gb = rgbcp + (size_t)b * PP * C2 + g * CG + lk * 8;
    const unsigned short* wg = dwF + (size_t)g * 9 * 2 * 64 * 8 + (size_t)l * 8;

    #pragma unroll
    for (int t = 0; t < 9; ++t) {
        float fy = floorf(sy[t]), fx = floorf(sx[t]);
        int iy = (int)fy, ix = (int)fx;
        float wy = sy[t] - fy, wx = sx[t] - fx;

        float my0 = ((unsigned)iy       < HH) ? 1.f : 0.f;
        float my1 = ((unsigned)(iy + 1) < HH) ? 1.f : 0.f;
        float mx0 = ((unsigned)ix       < WW) ? 1.f : 0.f;
        float mx1 = ((unsigned)(ix + 1) < WW) ? 1.f : 0.f;
        float w00 = (1.f - wy) * (1.f - wx) * my0 * mx0;
        float w01 = (1.f - wy) * wx         * my0 * mx1;
        float w10 = wy * (1.f - wx)         * my1 * mx0;
        float w11 = wy * wx                 * my1 * mx1;

        int cy0 = min(max(iy, 0), HH - 1) + 1;
        int cy1 = min(max(iy + 1, 0), HH - 1) + 1;
        int cx0 = min(max(ix, 0), WW - 1) + 1;
        int cx1 = min(max(ix + 1, 0), WW - 1) + 1;

        uint4 q00, q01, q10, q11;
        if (cy0 >= r0 && cy1 <= r0 + 4) {     // fast path: staged window
            const int ry0 = (cy0 - r0) * 82, ry1 = (cy1 - r0) * 82;
            q00 = *(const uint4*)&st[(ry0 + cx0) * DSTP + lk * 8];
            q01 = *(const uint4*)&st[(ry0 + cx1) * DSTP + lk * 8];
            q10 = *(const uint4*)&st[(ry1 + cx0) * DSTP + lk * 8];
            q11 = *(const uint4*)&st[(ry1 + cx1) * DSTP + lk * 8];
        } else {                               // rare: large offset
            q00 = *(const uint4*)(gb + ((size_t)cy0 * PD + cx0) * C2);
            q01 = *(const uint4*)(gb + ((size_t)cy0 * PD + cx1) * C2);
            q10 = *(const uint4*)(gb + ((size_t)cy1 * PD + cx0) * C2);
            q11 = *(const uint4*)(gb + ((size_t)cy1 * PD + cx1) * C2);
        }

        float sm[8];
        #pragma unroll
        for (int i = 0; i < 8; ++i) sm[i] = 0.f;
#define ACCQ(Q, WGT) { \
        unsigned uu[4] = {Q.x, Q.y, Q.z, Q.w}; \
        _Pragma("unroll") \
        for (int j = 0; j < 4; ++j) { \
            float f0 = __uint_as_float(uu[j] << 16); \
            float f1 = __uint_as_float(uu[j] & 0xffff0000u); \
            sm[2 * j]     = fmaf(f0, WGT, sm[2 * j]); \
            sm[2 * j + 1] = fmaf(f1, WGT, sm[2 * j + 1]); \
        } }
        ACCQ(q00, w00) ACCQ(q01, w01) ACCQ(q10, w10) ACCQ(q11, w11)
#undef ACCQ

        union { bf16x8 v; unsigned u[4]; } af;
        #pragma unroll
        for (int j = 0; j < 4; ++j)
            asm volatile("v_cvt_pk_bf16_f32 %0, %1, %2"
                         : "=v"(af.u[j]) : "v"(sm[2 * j]), "v"(sm[2 * j + 1]));

        bf16x8 bf0 = *(const bf16x8*)(wg + (size_t)t * 2 * 64 * 8);
        bf16x8 bf1 = *(const bf16x8*)(wg + (size_t)t * 2 * 64 * 8 + 64 * 8);
        acc0 = __builtin_amdgcn_mfma_f32_16x16x32_bf16(af.v, bf0, acc0, 0, 0, 0);
        acc1 = __builtin_amdgcn_mfma_f32_16x16x32_bf16(af.v, bf1, acc1, 0, 0, 0);
    }

    {
        const int oc = g * CG + l15;
        const float bias = db[oc];
        float4 v;
        v.x = acc0[0] + bias; v.y = acc0[1] + bias;
        v.z = acc0[2] + bias; v.w = acc0[3] + bias;
        *(float4*)(out + ((size_t)b * CIN + oc) * HW + p0 + lk * 4) = v;
    }
    {
        const int oc = g * CG + 16 + l15;
        const float bias = db[oc];
        float4 v;
        v.x = acc1[0] + bias; v.y = acc1[1] + bias;
        v.z = acc1[2] + bias; v.w = acc1[3] + bias;
        *(float4*)(out + ((size_t)b * CIN + oc) * HW + p0 + lk * 4) = v;
    }
}

extern "C" void kernel_launch(void* const* d_in, const int* in_sizes, int n_in,
                              void* d_out, int out_size, void* d_ws, size_t ws_size,
                              hipStream_t stream) {
    const float* rgb     = (const float*)d_in[0];
    const float* thermal = (const float*)d_in[1];
    const float* w1      = (const float*)d_in[2];
    const float* b1      = (const float*)d_in[3];
    const float* w2      = (const float*)d_in[4];
    const float* b2      = (const float*)d_in[5];
    const float* dw      = (const float*)d_in[6];
    const float* db      = (const float*)d_in[7];
    const float* osc     = (const float*)d_in[8];

    char* w = (char*)d_ws;
    unsigned short* rgbcp = (unsigned short*)w;  w += (size_t)BB * PP * C2 * 2;
    unsigned short* hdnp  = (unsigned short*)w;  w += (size_t)BB * PP * MID * 2;
    float*          offs  = (float*)w;           w += (size_t)BB * OFFC * HW * 4;
    unsigned short* w1F   = (unsigned short*)w;  w += (size_t)147456 * 2;
    unsigned short* w2F   = (unsigned short*)w;  w += (size_t)46080 * 2;
    unsigned short* dwF   = (unsigned short*)w;  w += (size_t)36864 * 2;
    float* out = (float*)d_out;

    zero_borders<<<dim3((BB * 324 + 255) / 256), 256, 0, stream>>>(rgbcp, hdnp);
    pack_rgbc<<<dim3(BB * HH * 8), 256, 0, stream>>>(rgb, thermal, rgbcp);
    pack_weights<<<dim3(900), 256, 0, stream>>>(w1, w2, dw, w1F, w2F, dwF);
    conv1_mfma<<<dim3(BB * HH), 256, 0, stream>>>(rgbcp, w1F, b1, hdnp);
    conv2_mfma<<<dim3(BB * HH), 320, 0, stream>>>(hdnp, w2F, b2, osc, offs);
    deform_kernel<<<dim3(BB * HH * NG), 320, 0, stream>>>(rgbcp, offs, dwF, db, out);
}

// Round 10
// 102.340 us; speedup vs baseline: 3.0255x; 1.0748x over previous
//
#include <hip/hip_runtime.h>

#define HH 80
#define WW 80
#define BB 8
#define CIN 128
#define C2 256
#define MID 64
#define OFFC 72
#define NG 4
#define CG 32
#define HW (HH * WW)
#define PD 82           // padded spatial dim
#define PP (PD * PD)    // padded pixels per image
#define STP 72          // conv LDS px stride in channels
#define DSTP 40         // deform LDS px stride in shorts (80 B)

typedef short bf16x8 __attribute__((ext_vector_type(8)));
typedef float f32x4  __attribute__((ext_vector_type(4)));

static __device__ __forceinline__ unsigned short f2bf(float f) {
    union { float f; unsigned u; } v; v.f = f;
    unsigned r = v.u + 0x7fffu + ((v.u >> 16) & 1u);   // RNE
    return (unsigned short)(r >> 16);
}

// ---------------- setup: weight packs + zero borders (fused) ----------------
// bid < 900: pack w1F/w2F/dwF fragment layouts; bid >= 900: zero borders.
__global__ __launch_bounds__(256) void setup_kernel(
    const float* __restrict__ w1, const float* __restrict__ w2,
    const float* __restrict__ dw,
    unsigned short* __restrict__ w1F, unsigned short* __restrict__ w2F,
    unsigned short* __restrict__ dwF,
    unsigned short* __restrict__ rgbcp, unsigned short* __restrict__ hdnp)
{
    if (blockIdx.x < 900) {
        int idx = blockIdx.x * 256 + threadIdx.x;
        if (idx < 147456) {
            int e  = idx & 7;
            int t1 = idx >> 3;  int l  = t1 & 63;
            int t2 = t1 >> 6;   int cb = t2 & 1;
            int t3 = t2 >> 1;   int tap = t3 % 9;
            int t4 = t3 / 9;    int cc = t4 & 3;  int nf = t4 >> 2;
            int oc = nf * 16 + (l & 15);
            int ic = cc * 64 + cb * 32 + (l >> 4) * 8 + e;
            w1F[idx] = f2bf(w1[((size_t)oc * C2 + ic) * 9 + tap]);
        } else if (idx < 193536) {
            int i2 = idx - 147456;
            int e  = i2 & 7;
            int t1 = i2 >> 3;  int l  = t1 & 63;
            int t2 = t1 >> 6;  int cb = t2 & 1;
            int t3 = t2 >> 1;  int tap = t3 % 9;
            int nf = t3 / 9;
            int oc = nf * 16 + (l & 15);
            int ic = cb * 32 + (l >> 4) * 8 + e;
            float v = (oc < OFFC) ? w2[((size_t)oc * MID + ic) * 9 + tap] : 0.f;
            w2F[i2] = f2bf(v);
        } else {
            int i3 = idx - 193536;
            int e   = i3 & 7;
            int l   = (i3 >> 3) & 63;
            int ocb = (i3 >> 9) & 1;
            int gt  = i3 >> 10;
            int tap = gt % 9, g = gt / 9;
            int oc = ocb * 16 + (l & 15);
            int c  = (l >> 4) * 8 + e;
            dwF[i3] = f2bf(dw[((size_t)(g * CG + oc) * CG + c) * 9 + tap]);
        }
    } else {
        int idx = (blockIdx.x - 900) * 256 + threadIdx.x;
        if (idx >= BB * 324) return;
        int b = idx / 324, e = idx - (idx / 324) * 324;
        int y, x;
        if (e < 82)       { y = 0;  x = e; }
        else if (e < 164) { y = 81; x = e - 82; }
        else if (e < 244) { y = e - 164 + 1; x = 0; }
        else              { y = e - 244 + 1; x = 81; }
        size_t pos = (size_t)b * PP + y * PD + x;
        uint4 z = {0, 0, 0, 0};
        uint4* r = (uint4*)(rgbcp + pos * C2);
        #pragma unroll
        for (int i = 0; i < 32; ++i) r[i] = z;
        uint4* h = (uint4*)(hdnp + pos * MID);
        #pragma unroll
        for (int i = 0; i < 8; ++i) h[i] = z;
    }
}

// ---------------- pack concat(rgb,thermal) NCHW fp32 -> padded NHWC bf16 ------
__global__ __launch_bounds__(256) void pack_rgbc(
    const float* __restrict__ rgb, const float* __restrict__ thermal,
    unsigned short* __restrict__ rgbcp)
{
    const int bid = blockIdx.x;
    const int ct  = bid & 7;
    const int rem = bid >> 3;
    const int y = rem % HH, b = rem / HH;
    const float* src = (ct < 4) ? rgb : thermal;
    const int cbase = (ct & 3) * 32;

    __shared__ float tile[32][81];
    for (int e = threadIdx.x; e < 32 * WW; e += 256) {
        int c = e / WW, x = e - c * WW;
        tile[c][x] = src[((size_t)(b * CIN + cbase + c) * HH + y) * WW + x];
    }
    __syncthreads();
    for (int e = threadIdx.x; e < 16 * WW; e += 256) {
        int x = e >> 4, cp = (e & 15) * 2;
        unsigned lo = f2bf(tile[cp][x]);
        unsigned hi = f2bf(tile[cp + 1][x]);
        *(unsigned*)(rgbcp + ((size_t)b * PP + (size_t)(y + 1) * PD + x + 1) * C2 + ct * 32 + cp)
            = lo | (hi << 16);
    }
}

// ---------------- conv1: implicit GEMM, LDS-staged A, fragment-packed B -------
// grid: B*H (b = bid&7 -> XCD-chunked); block 256 = 4 waves (nf = 16 oc each)
__global__ __launch_bounds__(256) void conv1_mfma(
    const unsigned short* __restrict__ rgbcp, const unsigned short* __restrict__ w1F,
    const float* __restrict__ b1, unsigned short* __restrict__ hdnp)
{
    const int by = blockIdx.x;
    const int b = by & 7, y = by >> 3;
    const int tid = threadIdx.x;
    const int nf = tid >> 6;
    const int l = tid & 63, l15 = l & 15, lk = l >> 4;

    __shared__ __align__(16) unsigned short st[3 * 82 * STP];   // 35.4 KB

    f32x4 acc[5];
    #pragma unroll
    for (int i = 0; i < 5; ++i) acc[i] = (f32x4){0.f, 0.f, 0.f, 0.f};

    const size_t rowbase = (size_t)b * PP + (size_t)y * PD;   // padded row y = out row -1

    for (int cc = 0; cc < 4; ++cc) {
        __syncthreads();
        for (int e = tid; e < 3 * 82 * 8; e += 256) {
            int r   = e / 656;
            int rem = e - r * 656;
            int px  = rem >> 3;
            int c8  = rem & 7;
            const uint4 v = *(const uint4*)(rgbcp + (rowbase + (size_t)r * PD + px) * C2 + cc * 64 + c8 * 8);
            *(uint4*)&st[(r * 82 + px) * STP + c8 * 8] = v;
        }
        __syncthreads();

        const unsigned short* bw = w1F + (((size_t)(nf * 4 + cc) * 9) * 2 * 64) * 8;
        #pragma unroll
        for (int tap = 0; tap < 9; ++tap) {
            const int ky = tap / 3, kx = tap - ky * 3;
            #pragma unroll
            for (int cb = 0; cb < 2; ++cb) {
                bf16x8 bf = *(const bf16x8*)(bw + ((size_t)(tap * 2 + cb) * 64 + l) * 8);
                #pragma unroll
                for (int mf = 0; mf < 5; ++mf) {
                    bf16x8 af = *(const bf16x8*)&st[(ky * 82 + mf * 16 + l15 + kx) * STP + cb * 32 + lk * 8];
                    acc[mf] = __builtin_amdgcn_mfma_f32_16x16x32_bf16(af, bf, acc[mf], 0, 0, 0);
                }
            }
        }
    }

    const int oc = nf * 16 + l15;
    const float bias = b1[oc];
    unsigned short* ob = hdnp + ((size_t)b * PP + (size_t)(y + 1) * PD + 1) * MID + oc;
    #pragma unroll
    for (int mf = 0; mf < 5; ++mf)
        #pragma unroll
        for (int r = 0; r < 4; ++r) {
            float v = acc[mf][r] + bias;
            v = v > 0.f ? v : 0.f;
            ob[(size_t)(mf * 16 + lk * 4 + r) * MID] = f2bf(v);
        }
}

// ---------------- conv2: implicit GEMM, LDS-staged A, fragment-packed B -------
// grid: B*H (b = bid&7); block 320 = 5 waves (nf = 16 oc of 80 padded)
__global__ __launch_bounds__(320) void conv2_mfma(
    const unsigned short* __restrict__ hdnp, const unsigned short* __restrict__ w2F,
    const float* __restrict__ b2, const float* __restrict__ scale_p,
    float* __restrict__ offs)
{
    const int by = blockIdx.x;
    const int b = by & 7, y = by >> 3;
    const int tid = threadIdx.x;
    const int nf = tid / 64;
    const int l = tid & 63, l15 = l & 15, lk = l >> 4;

    __shared__ __align__(16) unsigned short st[3 * 82 * STP];

    f32x4 acc[5];
    #pragma unroll
    for (int i = 0; i < 5; ++i) acc[i] = (f32x4){0.f, 0.f, 0.f, 0.f};

    const size_t rowbase = (size_t)b * PP + (size_t)y * PD;

    for (int e = tid; e < 3 * 82 * 8; e += 320) {
        int r   = e / 656;
        int rem = e - r * 656;
        int px  = rem >> 3;
        int c8  = rem & 7;
        const uint4 v = *(const uint4*)(hdnp + (rowbase + (size_t)r * PD + px) * MID + c8 * 8);
        *(uint4*)&st[(r * 82 + px) * STP + c8 * 8] = v;
    }
    __syncthreads();

    const unsigned short* bw = w2F + ((size_t)nf * 9 * 2 * 64) * 8;
    #pragma unroll
    for (int tap = 0; tap < 9; ++tap) {
        const int ky = tap / 3, kx = tap - ky * 3;
        #pragma unroll
        for (int cb = 0; cb < 2; ++cb) {
            bf16x8 bf = *(const bf16x8*)(bw + ((size_t)(tap * 2 + cb) * 64 + l) * 8);
            #pragma unroll
            for (int mf = 0; mf < 5; ++mf) {
                bf16x8 af = *(const bf16x8*)&st[(ky * 82 + mf * 16 + l15 + kx) * STP + cb * 32 + lk * 8];
                acc[mf] = __builtin_amdgcn_mfma_f32_16x16x32_bf16(af, bf, acc[mf], 0, 0, 0);
            }
        }
    }

    const int oc = nf * 16 + l15;
    if (oc < OFFC) {
        const float scale = scale_p[0];
        const float bias = b2[oc];
        float* ob = offs + ((size_t)b * OFFC + oc) * HW + y * WW;
        #pragma unroll
        for (int mf = 0; mf < 5; ++mf) {
            float4 v;
            v.x = (acc[mf][0] + bias) * scale;
            v.y = (acc[mf][1] + bias) * scale;
            v.z = (acc[mf][2] + bias) * scale;
            v.w = (acc[mf][3] + bias) * scale;
            *(float4*)(ob + mf * 16 + lk * 4) = v;
        }
    }
}

// ---------------- deformable conv 3x3: 2-row LDS window + MFMA mix -----------
// block = (b, y-pair, g): 640 thr = 10 waves = 2 rows x 5 x-tiles of 16 px.
// Stage padded rows r0..r0+5 (group slice, 39.4 KB); gathers hit LDS; per-lane
// global fallback only when |offset| >= ~1.
__global__ __launch_bounds__(640, 6) void deform_kernel(
    const unsigned short* __restrict__ rgbcp, const float* __restrict__ offs,
    const unsigned short* __restrict__ dwF, const float* __restrict__ db,
    float* __restrict__ out)
{
    const int b = blockIdx.x & 7;
    const int rem = blockIdx.x >> 3;      // 0..159 (y2 inner, g outer)
    const int y2 = rem % 40;
    const int g  = rem / 40;
    const int wv64 = threadIdx.x >> 6;    // 0..9
    const int h  = (wv64 >= 5) ? 1 : 0;   // row within pair
    const int wv = wv64 - h * 5;          // x-tile 0..4
    const int l = threadIdx.x & 63, l15 = l & 15, lk = l >> 4;

    const int y0 = y2 * 2;
    const int y  = y0 + h;
    const int x  = wv * 16 + l15;
    const int p  = y * WW + x;
    const int p0 = y * WW + wv * 16;
    const int r0 = min(max(y0 - 1, 0), PD - 6);    // staged padded rows r0..r0+5

    __shared__ __align__(16) unsigned short st[6 * 82 * DSTP];   // 39.4 KB

    // ---- stage: 6 rows x 82 px x 32 ch (64 B/px slice) ----
    const unsigned short* gsrc = rgbcp + ((size_t)b * PP + (size_t)r0 * PD) * C2 + g * CG;
    for (int e = threadIdx.x; e < 6 * 82 * 4; e += 640) {
        int r  = e / 328;
        int rm = e - r * 328;
        int px = rm >> 2, c8 = rm & 3;
        uint4 v = *(const uint4*)(gsrc + ((size_t)r * PD + px) * C2 + c8 * 8);
        *(uint4*)&st[(r * 82 + px) * DSTP + c8 * 8] = v;
    }
    __syncthreads();

    // ---- offsets up front ----
    const float* ob = offs + ((size_t)b * OFFC + g * 18) * HW + p;
    float sy[9], sx[9];
    #pragma unroll
    for (int t = 0; t < 9; ++t) {
        float offy = ob[(size_t)(2 * t) * HW];
        float offx = ob[(size_t)(2 * t + 1) * HW];
        sy[t] = (float)(y + t / 3 - 1) + offy;
        sx[t] = (float)(x + t % 3 - 1) + offx;
    }

    f32x4 acc0 = (f32x4){0.f, 0.f, 0.f, 0.f};
    f32x4 acc1 = (f32x4){0.f, 0.f, 0.f, 0.f};
    const unsigned short* gb = rgbcp + (size_t)b * PP * C2 + g * CG + lk * 8;
    const unsigned short* wg = dwF + (size_t)g * 9 * 2 * 64 * 8 + (size_t)l * 8;

    #pragma unroll
    for (int t = 0; t < 9; ++t) {
        float fy = floorf(sy[t]), fx = floorf(sx[t]);
        int iy = (int)fy, ix = (int)fx;
        float wy = sy[t] - fy, wx = sx[t] - fx;

        float my0 = ((unsigned)iy       < HH) ? 1.f : 0.f;
        float my1 = ((unsigned)(iy + 1) < HH) ? 1.f : 0.f;
        float mx0 = ((unsigned)ix       < WW) ? 1.f : 0.f;
        float mx1 = ((unsigned)(ix + 1) < WW) ? 1.f : 0.f;
        float w00 = (1.f - wy) * (1.f - wx) * my0 * mx0;
        float w01 = (1.f - wy) * wx         * my0 * mx1;
        float w10 = wy * (1.f - wx)         * my1 * mx0;
        float w11 = wy * wx                 * my1 * mx1;

        int cy0 = min(max(iy, 0), HH - 1) + 1;
        int cy1 = min(max(iy + 1, 0), HH - 1) + 1;
        int cx0 = min(max(ix, 0), WW - 1) + 1;
        int cx1 = min(max(ix + 1, 0), WW - 1) + 1;

        uint4 q00, q01, q10, q11;
        if (cy0 >= r0 && cy1 <= r0 + 5) {     // fast path: staged window
            const int ry0 = (cy0 - r0) * 82, ry1 = (cy1 - r0) * 82;
            q00 = *(const uint4*)&st[(ry0 + cx0) * DSTP + lk * 8];
            q01 = *(const uint4*)&st[(ry0 + cx1) * DSTP + lk * 8];
            q10 = *(const uint4*)&st[(ry1 + cx0) * DSTP + lk * 8];
            q11 = *(const uint4*)&st[(ry1 + cx1) * DSTP + lk * 8];
        } else {                               // rare: large offset
            q00 = *(const uint4*)(gb + ((size_t)cy0 * PD + cx0) * C2);
            q01 = *(const uint4*)(gb + ((size_t)cy0 * PD + cx1) * C2);
            q10 = *(const uint4*)(gb + ((size_t)cy1 * PD + cx0) * C2);
            q11 = *(const uint4*)(gb + ((size_t)cy1 * PD + cx1) * C2);
        }

        float sm[8];
        #pragma unroll
        for (int i = 0; i < 8; ++i) sm[i] = 0.f;
#define ACCQ(Q, WGT) { \
        unsigned uu[4] = {Q.x, Q.y, Q.z, Q.w}; \
        _Pragma("unroll") \
        for (int j = 0; j < 4; ++j) { \
            float f0 = __uint_as_float(uu[j] << 16); \
            float f1 = __uint_as_float(uu[j] & 0xffff0000u); \
            sm[2 * j]     = fmaf(f0, WGT, sm[2 * j]); \
            sm[2 * j + 1] = fmaf(f1, WGT, sm[2 * j + 1]); \
        } }
        ACCQ(q00, w00) ACCQ(q01, w01) ACCQ(q10, w10) ACCQ(q11, w11)
#undef ACCQ

        union { bf16x8 v; unsigned u[4]; } af;
        #pragma unroll
        for (int j = 0; j < 4; ++j)
            asm volatile("v_cvt_pk_bf16_f32 %0, %1, %2"
                         : "=v"(af.u[j]) : "v"(sm[2 * j]), "v"(sm[2 * j + 1]));

        bf16x8 bf0 = *(const bf16x8*)(wg + (size_t)t * 2 * 64 * 8);
        bf16x8 bf1 = *(const bf16x8*)(wg + (size_t)t * 2 * 64 * 8 + 64 * 8);
        acc0 = __builtin_amdgcn_mfma_f32_16x16x32_bf16(af.v, bf0, acc0, 0, 0, 0);
        acc1 = __builtin_amdgcn_mfma_f32_16x16x32_bf16(af.v, bf1, acc1, 0, 0, 0);
    }

    {
        const int oc = g * CG + l15;
        const float bias = db[oc];
        float4 v;
        v.x = acc0[0] + bias; v.y = acc0[1] + bias;
        v.z = acc0[2] + bias; v.w = acc0[3] + bias;
        *(float4*)(out + ((size_t)b * CIN + oc) * HW + p0 + lk * 4) = v;
    }
    {
        const int oc = g * CG + 16 + l15;
        const float bias = db[oc];
        float4 v;
        v.x = acc1[0] + bias; v.y = acc1[1] + bias;
        v.z = acc1[2] + bias; v.w = acc1[3] + bias;
        *(float4*)(out + ((size_t)b * CIN + oc) * HW + p0 + lk * 4) = v;
    }
}

extern "C" void kernel_launch(void* const* d_in, const int* in_sizes, int n_in,
                              void* d_out, int out_size, void* d_ws, size_t ws_size,
                              hipStream_t stream) {
    const float* rgb     = (const float*)d_in[0];
    const float* thermal = (const float*)d_in[1];
    const float* w1      = (const float*)d_in[2];
    const float* b1      = (const float*)d_in[3];
    const float* w2      = (const float*)d_in[4];
    const float* b2      = (const float*)d_in[5];
    const float* dw      = (const float*)d_in[6];
    const float* db      = (const float*)d_in[7];
    const float* osc     = (const float*)d_in[8];

    char* w = (char*)d_ws;
    unsigned short* rgbcp = (unsigned short*)w;  w += (size_t)BB * PP * C2 * 2;
    unsigned short* hdnp  = (unsigned short*)w;  w += (size_t)BB * PP * MID * 2;
    float*          offs  = (float*)w;           w += (size_t)BB * OFFC * HW * 4;
    unsigned short* w1F   = (unsigned short*)w;  w += (size_t)147456 * 2;
    unsigned short* w2F   = (unsigned short*)w;  w += (size_t)46080 * 2;
    unsigned short* dwF   = (unsigned short*)w;  w += (size_t)36864 * 2;
    float* out = (float*)d_out;

    setup_kernel<<<dim3(911), 256, 0, stream>>>(w1, w2, dw, w1F, w2F, dwF, rgbcp, hdnp);
    pack_rgbc<<<dim3(BB * HH * 8), 256, 0, stream>>>(rgb, thermal, rgbcp);
    conv1_mfma<<<dim3(BB * HH), 256, 0, stream>>>(rgbcp, w1F, b1, hdnp);
    conv2_mfma<<<dim3(BB * HH), 320, 0, stream>>>(hdnp, w2F, b2, osc, offs);
    deform_kernel<<<dim3(BB * 40 * NG), 640, 0, stream>>>(rgbcp, offs, dwF, db, out);
}

// Round 11
// 101.426 us; speedup vs baseline: 3.0528x; 1.0090x over previous
//
#include <hip/hip_runtime.h>

#define HH 80
#define WW 80
#define BB 8
#define CIN 128
#define C2 256
#define MID 64
#define OFFC 72
#define NG 4
#define CG 32
#define HW (HH * WW)
#define PD 82           // padded spatial dim
#define PP (PD * PD)    // padded pixels per image
#define STP 72          // conv LDS px stride in channels
#define DSTP 40         // deform LDS px stride in shorts (80 B)

typedef short bf16x8 __attribute__((ext_vector_type(8)));
typedef float f32x4  __attribute__((ext_vector_type(4)));
typedef float f32x2  __attribute__((ext_vector_type(2)));

static __device__ __forceinline__ unsigned short f2bf(float f) {
    union { float f; unsigned u; } v; v.f = f;
    unsigned r = v.u + 0x7fffu + ((v.u >> 16) & 1u);   // RNE
    return (unsigned short)(r >> 16);
}

// ---------------- prep: weight packs + borders + rgbc pack (one kernel) -------
// bid < 450          : pack w1F/w2F/dwF fragment layouts (idx = bid*512+tid)
// bid in [450,458)   : zero borders of rgbcp/hdnp
// bid >= 458         : pack concat(rgb,thermal) NCHW fp32 -> padded NHWC bf16,
//                      one (b,y) row per block, fully coalesced 512B/px writes
__global__ __launch_bounds__(512) void prep_kernel(
    const float* __restrict__ w1, const float* __restrict__ w2,
    const float* __restrict__ dw, const float* __restrict__ rgb,
    const float* __restrict__ thermal,
    unsigned short* __restrict__ w1F, unsigned short* __restrict__ w2F,
    unsigned short* __restrict__ dwF,
    unsigned short* __restrict__ rgbcp, unsigned short* __restrict__ hdnp)
{
    if (blockIdx.x < 450) {
        int idx = blockIdx.x * 512 + threadIdx.x;
        if (idx < 147456) {
            int e  = idx & 7;
            int t1 = idx >> 3;  int l  = t1 & 63;
            int t2 = t1 >> 6;   int cb = t2 & 1;
            int t3 = t2 >> 1;   int tap = t3 % 9;
            int t4 = t3 / 9;    int cc = t4 & 3;  int nf = t4 >> 2;
            int oc = nf * 16 + (l & 15);
            int ic = cc * 64 + cb * 32 + (l >> 4) * 8 + e;
            w1F[idx] = f2bf(w1[((size_t)oc * C2 + ic) * 9 + tap]);
        } else if (idx < 193536) {
            int i2 = idx - 147456;
            int e  = i2 & 7;
            int t1 = i2 >> 3;  int l  = t1 & 63;
            int t2 = t1 >> 6;  int cb = t2 & 1;
            int t3 = t2 >> 1;  int tap = t3 % 9;
            int nf = t3 / 9;
            int oc = nf * 16 + (l & 15);
            int ic = cb * 32 + (l >> 4) * 8 + e;
            float v = (oc < OFFC) ? w2[((size_t)oc * MID + ic) * 9 + tap] : 0.f;
            w2F[i2] = f2bf(v);
        } else {
            int i3 = idx - 193536;
            int e   = i3 & 7;
            int l   = (i3 >> 3) & 63;
            int ocb = (i3 >> 9) & 1;
            int gt  = i3 >> 10;
            int tap = gt % 9, g = gt / 9;
            int oc = ocb * 16 + (l & 15);
            int c  = (l >> 4) * 8 + e;
            dwF[i3] = f2bf(dw[((size_t)(g * CG + oc) * CG + c) * 9 + tap]);
        }
    } else if (blockIdx.x < 458) {
        int idx = (blockIdx.x - 450) * 512 + threadIdx.x;
        if (idx >= BB * 324) return;
        int b = idx / 324, e = idx - (idx / 324) * 324;
        int y, x;
        if (e < 82)       { y = 0;  x = e; }
        else if (e < 164) { y = 81; x = e - 82; }
        else if (e < 244) { y = e - 164 + 1; x = 0; }
        else              { y = e - 244 + 1; x = 81; }
        size_t pos = (size_t)b * PP + y * PD + x;
        uint4 z = {0, 0, 0, 0};
        uint4* r = (uint4*)(rgbcp + pos * C2);
        #pragma unroll
        for (int i = 0; i < 32; ++i) r[i] = z;
        uint4* h = (uint4*)(hdnp + pos * MID);
        #pragma unroll
        for (int i = 0; i < 8; ++i) h[i] = z;
    } else {
        const int pb = blockIdx.x - 458;      // 0..639
        const int b = pb & 7, y = pb >> 3;
        __shared__ unsigned tile[128 * 84];   // [ch-pair][px], 43 KB

        // load NCHW fp32 (coalesced row segments), convert, pack ch-pairs
        for (int e = threadIdx.x; e < 128 * 20; e += 512) {
            int c2 = e / 20, p4 = e - c2 * 20;
            int ch0 = 2 * c2;
            const float* srcA = (ch0 < CIN)
                ? rgb     + ((size_t)(b * CIN + ch0)       * HH + y) * WW
                : thermal + ((size_t)(b * CIN + ch0 - CIN) * HH + y) * WW;
            float4 a0 = *(const float4*)(srcA + p4 * 4);
            float4 a1 = *(const float4*)(srcA + HW + p4 * 4);
            unsigned w0 = f2bf(a0.x) | ((unsigned)f2bf(a1.x) << 16);
            unsigned w1r = f2bf(a0.y) | ((unsigned)f2bf(a1.y) << 16);
            unsigned w2r = f2bf(a0.z) | ((unsigned)f2bf(a1.z) << 16);
            unsigned w3 = f2bf(a0.w) | ((unsigned)f2bf(a1.w) << 16);
            uint4 v = {w0, w1r, w2r, w3};
            *(uint4*)&tile[c2 * 84 + p4 * 4] = v;
        }
        __syncthreads();

        // store: each wave writes one pixel's full 512B (perfectly coalesced)
        for (int e = threadIdx.x; e < 80 * 64; e += 512) {
            int px = e >> 6, c4 = e & 63;
            uint2 v;
            v.x = tile[(2 * c4) * 84 + px];
            v.y = tile[(2 * c4 + 1) * 84 + px];
            *(uint2*)(rgbcp + ((size_t)b * PP + (size_t)(y + 1) * PD + px + 1) * C2 + c4 * 4) = v;
        }
    }
}

// ---------------- conv1: implicit GEMM, LDS-staged A, fragment-packed B -------
// grid: B*H (b = bid&7 -> XCD-chunked); block 256 = 4 waves (nf = 16 oc each)
__global__ __launch_bounds__(256) void conv1_mfma(
    const unsigned short* __restrict__ rgbcp, const unsigned short* __restrict__ w1F,
    const float* __restrict__ b1, unsigned short* __restrict__ hdnp)
{
    const int by = blockIdx.x;
    const int b = by & 7, y = by >> 3;
    const int tid = threadIdx.x;
    const int nf = tid >> 6;
    const int l = tid & 63, l15 = l & 15, lk = l >> 4;

    __shared__ __align__(16) unsigned short st[3 * 82 * STP];   // 35.4 KB

    f32x4 acc[5];
    #pragma unroll
    for (int i = 0; i < 5; ++i) acc[i] = (f32x4){0.f, 0.f, 0.f, 0.f};

    const size_t rowbase = (size_t)b * PP + (size_t)y * PD;   // padded row y = out row -1

    for (int cc = 0; cc < 4; ++cc) {
        __syncthreads();
        for (int e = tid; e < 3 * 82 * 8; e += 256) {
            int r   = e / 656;
            int rem = e - r * 656;
            int px  = rem >> 3;
            int c8  = rem & 7;
            const uint4 v = *(const uint4*)(rgbcp + (rowbase + (size_t)r * PD + px) * C2 + cc * 64 + c8 * 8);
            *(uint4*)&st[(r * 82 + px) * STP + c8 * 8] = v;
        }
        __syncthreads();

        const unsigned short* bw = w1F + (((size_t)(nf * 4 + cc) * 9) * 2 * 64) * 8;
        #pragma unroll
        for (int tap = 0; tap < 9; ++tap) {
            const int ky = tap / 3, kx = tap - ky * 3;
            #pragma unroll
            for (int cb = 0; cb < 2; ++cb) {
                bf16x8 bf = *(const bf16x8*)(bw + ((size_t)(tap * 2 + cb) * 64 + l) * 8);
                #pragma unroll
                for (int mf = 0; mf < 5; ++mf) {
                    bf16x8 af = *(const bf16x8*)&st[(ky * 82 + mf * 16 + l15 + kx) * STP + cb * 32 + lk * 8];
                    acc[mf] = __builtin_amdgcn_mfma_f32_16x16x32_bf16(af, bf, acc[mf], 0, 0, 0);
                }
            }
        }
    }

    const int oc = nf * 16 + l15;
    const float bias = b1[oc];
    unsigned short* ob = hdnp + ((size_t)b * PP + (size_t)(y + 1) * PD + 1) * MID + oc;
    #pragma unroll
    for (int mf = 0; mf < 5; ++mf)
        #pragma unroll
        for (int r = 0; r < 4; ++r) {
            float v = acc[mf][r] + bias;
            v = v > 0.f ? v : 0.f;
            ob[(size_t)(mf * 16 + lk * 4 + r) * MID] = f2bf(v);
        }
}

// ---------------- conv2: implicit GEMM, LDS-staged A, fragment-packed B -------
// grid: B*H (b = bid&7); block 320 = 5 waves (nf = 16 oc of 80 padded)
__global__ __launch_bounds__(320) void conv2_mfma(
    const unsigned short* __restrict__ hdnp, const unsigned short* __restrict__ w2F,
    const float* __restrict__ b2, const float* __restrict__ scale_p,
    float* __restrict__ offs)
{
    const int by = blockIdx.x;
    const int b = by & 7, y = by >> 3;
    const int tid = threadIdx.x;
    const int nf = tid / 64;
    const int l = tid & 63, l15 = l & 15, lk = l >> 4;

    __shared__ __align__(16) unsigned short st[3 * 82 * STP];

    f32x4 acc[5];
    #pragma unroll
    for (int i = 0; i < 5; ++i) acc[i] = (f32x4){0.f, 0.f, 0.f, 0.f};

    const size_t rowbase = (size_t)b * PP + (size_t)y * PD;

    for (int e = tid; e < 3 * 82 * 8; e += 320) {
        int r   = e / 656;
        int rem = e - r * 656;
        int px  = rem >> 3;
        int c8  = rem & 7;
        const uint4 v = *(const uint4*)(hdnp + (rowbase + (size_t)r * PD + px) * MID + c8 * 8);
        *(uint4*)&st[(r * 82 + px) * STP + c8 * 8] = v;
    }
    __syncthreads();

    const unsigned short* bw = w2F + ((size_t)nf * 9 * 2 * 64) * 8;
    #pragma unroll
    for (int tap = 0; tap < 9; ++tap) {
        const int ky = tap / 3, kx = tap - ky * 3;
        #pragma unroll
        for (int cb = 0; cb < 2; ++cb) {
            bf16x8 bf = *(const bf16x8*)(bw + ((size_t)(tap * 2 + cb) * 64 + l) * 8);
            #pragma unroll
            for (int mf = 0; mf < 5; ++mf) {
                bf16x8 af = *(const bf16x8*)&st[(ky * 82 + mf * 16 + l15 + kx) * STP + cb * 32 + lk * 8];
                acc[mf] = __builtin_amdgcn_mfma_f32_16x16x32_bf16(af, bf, acc[mf], 0, 0, 0);
            }
        }
    }

    const int oc = nf * 16 + l15;
    if (oc < OFFC) {
        const float scale = scale_p[0];
        const float bias = b2[oc];
        float* ob = offs + ((size_t)b * OFFC + oc) * HW + y * WW;
        #pragma unroll
        for (int mf = 0; mf < 5; ++mf) {
            float4 v;
            v.x = (acc[mf][0] + bias) * scale;
            v.y = (acc[mf][1] + bias) * scale;
            v.z = (acc[mf][2] + bias) * scale;
            v.w = (acc[mf][3] + bias) * scale;
            *(float4*)(ob + mf * 16 + lk * 4) = v;
        }
    }
}

// ---------------- deformable conv 3x3: 2-row LDS window + MFMA mix -----------
// block = (b, y-pair, g): 640 thr = 10 waves = 2 rows x 5 x-tiles of 16 px.
// Stage padded rows r0..r0+5 (group slice, 39.4 KB); gathers hit LDS; per-lane
// global fallback only when |offset| >= ~1.
__global__ __launch_bounds__(640, 6) void deform_kernel(
    const unsigned short* __restrict__ rgbcp, const float* __restrict__ offs,
    const unsigned short* __restrict__ dwF, const float* __restrict__ db,
    float* __restrict__ out)
{
    const int b = blockIdx.x & 7;
    const int rem = blockIdx.x >> 3;      // 0..159 (y2 inner, g outer)
    const int y2 = rem % 40;
    const int g  = rem / 40;
    const int wv64 = threadIdx.x >> 6;    // 0..9
    const int h  = (wv64 >= 5) ? 1 : 0;   // row within pair
    const int wv = wv64 - h * 5;          // x-tile 0..4
    const int l = threadIdx.x & 63, l15 = l & 15, lk = l >> 4;

    const int y0 = y2 * 2;
    const int y  = y0 + h;
    const int x  = wv * 16 + l15;
    const int p  = y * WW + x;
    const int p0 = y * WW + wv * 16;
    const int r0 = min(max(y0 - 1, 0), PD - 6);    // staged padded rows r0..r0+5

    __shared__ __align__(16) unsigned short st[6 * 82 * DSTP];   // 39.4 KB

    // ---- stage: 6 rows x 82 px x 32 ch (64 B/px slice) ----
    const unsigned short* gsrc = rgbcp + ((size_t)b * PP + (size_t)r0 * PD) * C2 + g * CG;
    for (int e = threadIdx.x; e < 6 * 82 * 4; e += 640) {
        int r  = e / 328;
        int rm = e - r * 328;
        int px = rm >> 2, c8 = rm & 3;
        uint4 v = *(const uint4*)(gsrc + ((size_t)r * PD + px) * C2 + c8 * 8);
        *(uint4*)&st[(r * 82 + px) * DSTP + c8 * 8] = v;
    }
    __syncthreads();

    // ---- offsets up front ----
    const float* ob = offs + ((size_t)b * OFFC + g * 18) * HW + p;
    float sy[9], sx[9];
    #pragma unroll
    for (int t = 0; t < 9; ++t) {
        float offy = ob[(size_t)(2 * t) * HW];
        float offx = ob[(size_t)(2 * t + 1) * HW];
        sy[t] = (float)(y + t / 3 - 1) + offy;
        sx[t] = (float)(x + t % 3 - 1) + offx;
    }

    f32x4 acc0 = (f32x4){0.f, 0.f, 0.f, 0.f};
    f32x4 acc1 = (f32x4){0.f, 0.f, 0.f, 0.f};
    const unsigned short* gb = rgbcp + (size_t)b * PP * C2 + g * CG + lk * 8;
    const unsigned short* wg = dwF + (size_t)g * 9 * 2 * 64 * 8 + (size_t)l * 8;

    #pragma unroll
    for (int t = 0; t < 9; ++t) {
        float fy = floorf(sy[t]), fx = floorf(sx[t]);
        int iy = (int)fy, ix = (int)fx;
        float wy = sy[t] - fy, wx = sx[t] - fx;

        float my0 = ((unsigned)iy       < HH) ? 1.f : 0.f;
        float my1 = ((unsigned)(iy + 1) < HH) ? 1.f : 0.f;
        float mx0 = ((unsigned)ix       < WW) ? 1.f : 0.f;
        float mx1 = ((unsigned)(ix + 1) < WW) ? 1.f : 0.f;
        float w00 = (1.f - wy) * (1.f - wx) * my0 * mx0;
        float w01 = (1.f - wy) * wx         * my0 * mx1;
        float w10 = wy * (1.f - wx)         * my1 * mx0;
        float w11 = wy * wx                 * my1 * mx1;

        int cy0 = min(max(iy, 0), HH - 1) + 1;
        int cy1 = min(max(iy + 1, 0), HH - 1) + 1;
        int cx0 = min(max(ix, 0), WW - 1) + 1;
        int cx1 = min(max(ix + 1, 0), WW - 1) + 1;

        uint4 q00, q01, q10, q11;
        if (cy0 >= r0 && cy1 <= r0 + 5) {     // fast path: staged window
            const int ry0 = (cy0 - r0) * 82, ry1 = (cy1 - r0) * 82;
            q00 = *(const uint4*)&st[(ry0 + cx0) * DSTP + lk * 8];
            q01 = *(const uint4*)&st[(ry0 + cx1) * DSTP + lk * 8];
            q10 = *(const uint4*)&st[(ry1 + cx0) * DSTP + lk * 8];
            q11 = *(const uint4*)&st[(ry1 + cx1) * DSTP + lk * 8];
        } else {                               // rare: large offset
            q00 = *(const uint4*)(gb + ((size_t)cy0 * PD + cx0) * C2);
            q01 = *(const uint4*)(gb + ((size_t)cy0 * PD + cx1) * C2);
            q10 = *(const uint4*)(gb + ((size_t)cy1 * PD + cx0) * C2);
            q11 = *(const uint4*)(gb + ((size_t)cy1 * PD + cx1) * C2);
        }

        // packed-f32 bilinear accumulate (hope for v_pk_fma_f32)
        f32x2 sm2[4];
        #pragma unroll
        for (int i = 0; i < 4; ++i) sm2[i] = (f32x2){0.f, 0.f};
#define ACCQ(Q, WGT) { \
        unsigned uu[4] = {Q.x, Q.y, Q.z, Q.w}; \
        f32x2 wv2 = {WGT, WGT}; \
        _Pragma("unroll") \
        for (int j = 0; j < 4; ++j) { \
            f32x2 q; \
            q.x = __uint_as_float(uu[j] << 16); \
            q.y = __uint_as_float(uu[j] & 0xffff0000u); \
            sm2[j] += q * wv2; \
        } }
        ACCQ(q00, w00) ACCQ(q01, w01) ACCQ(q10, w10) ACCQ(q11, w11)
#undef ACCQ

        union { bf16x8 v; unsigned u[4]; } af;
        #pragma unroll
        for (int j = 0; j < 4; ++j)
            asm volatile("v_cvt_pk_bf16_f32 %0, %1, %2"
                         : "=v"(af.u[j]) : "v"(sm2[j].x), "v"(sm2[j].y));

        bf16x8 bf0 = *(const bf16x8*)(wg + (size_t)t * 2 * 64 * 8);
        bf16x8 bf1 = *(const bf16x8*)(wg + (size_t)t * 2 * 64 * 8 + 64 * 8);
        acc0 = __builtin_amdgcn_mfma_f32_16x16x32_bf16(af.v, bf0, acc0, 0, 0, 0);
        acc1 = __builtin_amdgcn_mfma_f32_16x16x32_bf16(af.v, bf1, acc1, 0, 0, 0);
    }

    {
        const int oc = g * CG + l15;
        const float bias = db[oc];
        float4 v;
        v.x = acc0[0] + bias; v.y = acc0[1] + bias;
        v.z = acc0[2] + bias; v.w = acc0[3] + bias;
        *(float4*)(out + ((size_t)b * CIN + oc) * HW + p0 + lk * 4) = v;
    }
    {
        const int oc = g * CG + 16 + l15;
        const float bias = db[oc];
        float4 v;
        v.x = acc1[0] + bias; v.y = acc1[1] + bias;
        v.z = acc1[2] + bias; v.w = acc1[3] + bias;
        *(float4*)(out + ((size_t)b * CIN + oc) * HW + p0 + lk * 4) = v;
    }
}

extern "C" void kernel_launch(void* const* d_in, const int* in_sizes, int n_in,
                              void* d_out, int out_size, void* d_ws, size_t ws_size,
                              hipStream_t stream) {
    const float* rgb     = (const float*)d_in[0];
    const float* thermal = (const float*)d_in[1];
    const float* w1      = (const float*)d_in[2];
    const float* b1      = (const float*)d_in[3];
    const float* w2      = (const float*)d_in[4];
    const float* b2      = (const float*)d_in[5];
    const float* dw      = (const float*)d_in[6];
    const float* db      = (const float*)d_in[7];
    const float* osc     = (const float*)d_in[8];

    char* w = (char*)d_ws;
    unsigned short* rgbcp = (unsigned short*)w;  w += (size_t)BB * PP * C2 * 2;
    unsigned short* hdnp  = (unsigned short*)w;  w += (size_t)BB * PP * MID * 2;
    float*          offs  = (float*)w;           w += (size_t)BB * OFFC * HW * 4;
    unsigned short* w1F   = (unsigned short*)w;  w += (size_t)147456 * 2;
    unsigned short* w2F   = (unsigned short*)w;  w += (size_t)46080 * 2;
    unsigned short* dwF   = (unsigned short*)w;  w += (size_t)36864 * 2;
    float* out = (float*)d_out;

    prep_kernel<<<dim3(1098), 512, 0, stream>>>(w1, w2, dw, rgb, thermal,
                                                w1F, w2F, dwF, rgbcp, hdnp);
    conv1_mfma<<<dim3(BB * HH), 256, 0, stream>>>(rgbcp, w1F, b1, hdnp);
    conv2_mfma<<<dim3(BB * HH), 320, 0, stream>>>(hdnp, w2F, b2, osc, offs);
    deform_kernel<<<dim3(BB * 40 * NG), 640, 0, stream>>>(rgbcp, offs, dwF, db, out);
}

// Round 12
// 99.184 us; speedup vs baseline: 3.1218x; 1.0226x over previous
//
#include <hip/hip_runtime.h>

#define HH 80
#define WW 80
#define BB 8
#define CIN 128
#define C2 256
#define MID 64
#define OFFC 72
#define NG 4
#define CG 32
#define HW (HH * WW)
#define PD 82           // padded spatial dim
#define PP (PD * PD)    // padded pixels per image
#define STP 72          // conv LDS px stride in channels
#define QSTRIDE 493     // deform LDS plane stride in 16B units

typedef short bf16x8 __attribute__((ext_vector_type(8)));
typedef float f32x4  __attribute__((ext_vector_type(4)));

static __device__ __forceinline__ unsigned short f2bf(float f) {
    union { float f; unsigned u; } v; v.f = f;
    unsigned r = v.u + 0x7fffu + ((v.u >> 16) & 1u);   // RNE
    return (unsigned short)(r >> 16);
}

// ---------------- prep: weight packs + borders + rgbc pack (one kernel) -------
__global__ __launch_bounds__(512) void prep_kernel(
    const float* __restrict__ w1, const float* __restrict__ w2,
    const float* __restrict__ dw, const float* __restrict__ rgb,
    const float* __restrict__ thermal,
    unsigned short* __restrict__ w1F, unsigned short* __restrict__ w2F,
    unsigned short* __restrict__ dwF,
    unsigned short* __restrict__ rgbcp, unsigned short* __restrict__ hdnp)
{
    if (blockIdx.x < 450) {
        int idx = blockIdx.x * 512 + threadIdx.x;
        if (idx < 147456) {
            int e  = idx & 7;
            int t1 = idx >> 3;  int l  = t1 & 63;
            int t2 = t1 >> 6;   int cb = t2 & 1;
            int t3 = t2 >> 1;   int tap = t3 % 9;
            int t4 = t3 / 9;    int cc = t4 & 3;  int nf = t4 >> 2;
            int oc = nf * 16 + (l & 15);
            int ic = cc * 64 + cb * 32 + (l >> 4) * 8 + e;
            w1F[idx] = f2bf(w1[((size_t)oc * C2 + ic) * 9 + tap]);
        } else if (idx < 193536) {
            int i2 = idx - 147456;
            int e  = i2 & 7;
            int t1 = i2 >> 3;  int l  = t1 & 63;
            int t2 = t1 >> 6;  int cb = t2 & 1;
            int t3 = t2 >> 1;  int tap = t3 % 9;
            int nf = t3 / 9;
            int oc = nf * 16 + (l & 15);
            int ic = cb * 32 + (l >> 4) * 8 + e;
            float v = (oc < OFFC) ? w2[((size_t)oc * MID + ic) * 9 + tap] : 0.f;
            w2F[i2] = f2bf(v);
        } else {
            int i3 = idx - 193536;
            int e   = i3 & 7;
            int l   = (i3 >> 3) & 63;
            int ocb = (i3 >> 9) & 1;
            int gt  = i3 >> 10;
            int tap = gt % 9, g = gt / 9;
            int oc = ocb * 16 + (l & 15);
            int c  = (l >> 4) * 8 + e;
            dwF[i3] = f2bf(dw[((size_t)(g * CG + oc) * CG + c) * 9 + tap]);
        }
    } else if (blockIdx.x < 458) {
        int idx = (blockIdx.x - 450) * 512 + threadIdx.x;
        if (idx >= BB * 324) return;
        int b = idx / 324, e = idx - (idx / 324) * 324;
        int y, x;
        if (e < 82)       { y = 0;  x = e; }
        else if (e < 164) { y = 81; x = e - 82; }
        else if (e < 244) { y = e - 164 + 1; x = 0; }
        else              { y = e - 244 + 1; x = 81; }
        size_t pos = (size_t)b * PP + y * PD + x;
        uint4 z = {0, 0, 0, 0};
        uint4* r = (uint4*)(rgbcp + pos * C2);
        #pragma unroll
        for (int i = 0; i < 32; ++i) r[i] = z;
        uint4* h = (uint4*)(hdnp + pos * MID);
        #pragma unroll
        for (int i = 0; i < 8; ++i) h[i] = z;
    } else {
        const int pb = blockIdx.x - 458;      // 0..639
        const int b = pb & 7, y = pb >> 3;
        __shared__ unsigned tile[128 * 84];   // [ch-pair][px], 43 KB

        for (int e = threadIdx.x; e < 128 * 20; e += 512) {
            int c2 = e / 20, p4 = e - c2 * 20;
            int ch0 = 2 * c2;
            const float* srcA = (ch0 < CIN)
                ? rgb     + ((size_t)(b * CIN + ch0)       * HH + y) * WW
                : thermal + ((size_t)(b * CIN + ch0 - CIN) * HH + y) * WW;
            float4 a0 = *(const float4*)(srcA + p4 * 4);
            float4 a1 = *(const float4*)(srcA + HW + p4 * 4);
            unsigned w0 = f2bf(a0.x) | ((unsigned)f2bf(a1.x) << 16);
            unsigned w1r = f2bf(a0.y) | ((unsigned)f2bf(a1.y) << 16);
            unsigned w2r = f2bf(a0.z) | ((unsigned)f2bf(a1.z) << 16);
            unsigned w3 = f2bf(a0.w) | ((unsigned)f2bf(a1.w) << 16);
            uint4 v = {w0, w1r, w2r, w3};
            *(uint4*)&tile[c2 * 84 + p4 * 4] = v;
        }
        __syncthreads();

        for (int e = threadIdx.x; e < 80 * 64; e += 512) {
            int px = e >> 6, c4 = e & 63;
            uint2 v;
            v.x = tile[(2 * c4) * 84 + px];
            v.y = tile[(2 * c4 + 1) * 84 + px];
            *(uint2*)(rgbcp + ((size_t)b * PP + (size_t)(y + 1) * PD + px + 1) * C2 + c4 * 4) = v;
        }
    }
}

// ---------------- conv1: implicit GEMM, LDS-staged A, fragment-packed B -------
__global__ __launch_bounds__(256) void conv1_mfma(
    const unsigned short* __restrict__ rgbcp, const unsigned short* __restrict__ w1F,
    const float* __restrict__ b1, unsigned short* __restrict__ hdnp)
{
    const int by = blockIdx.x;
    const int b = by & 7, y = by >> 3;
    const int tid = threadIdx.x;
    const int nf = tid >> 6;
    const int l = tid & 63, l15 = l & 15, lk = l >> 4;

    __shared__ __align__(16) unsigned short st[3 * 82 * STP];   // 35.4 KB

    f32x4 acc[5];
    #pragma unroll
    for (int i = 0; i < 5; ++i) acc[i] = (f32x4){0.f, 0.f, 0.f, 0.f};

    const size_t rowbase = (size_t)b * PP + (size_t)y * PD;

    for (int cc = 0; cc < 4; ++cc) {
        __syncthreads();
        for (int e = tid; e < 3 * 82 * 8; e += 256) {
            int r   = e / 656;
            int rem = e - r * 656;
            int px  = rem >> 3;
            int c8  = rem & 7;
            const uint4 v = *(const uint4*)(rgbcp + (rowbase + (size_t)r * PD + px) * C2 + cc * 64 + c8 * 8);
            *(uint4*)&st[(r * 82 + px) * STP + c8 * 8] = v;
        }
        __syncthreads();

        const unsigned short* bw = w1F + (((size_t)(nf * 4 + cc) * 9) * 2 * 64) * 8;
        #pragma unroll
        for (int tap = 0; tap < 9; ++tap) {
            const int ky = tap / 3, kx = tap - ky * 3;
            #pragma unroll
            for (int cb = 0; cb < 2; ++cb) {
                bf16x8 bf = *(const bf16x8*)(bw + ((size_t)(tap * 2 + cb) * 64 + l) * 8);
                #pragma unroll
                for (int mf = 0; mf < 5; ++mf) {
                    bf16x8 af = *(const bf16x8*)&st[(ky * 82 + mf * 16 + l15 + kx) * STP + cb * 32 + lk * 8];
                    acc[mf] = __builtin_amdgcn_mfma_f32_16x16x32_bf16(af, bf, acc[mf], 0, 0, 0);
                }
            }
        }
    }

    const int oc = nf * 16 + l15;
    const float bias = b1[oc];
    unsigned short* ob = hdnp + ((size_t)b * PP + (size_t)(y + 1) * PD + 1) * MID + oc;
    #pragma unroll
    for (int mf = 0; mf < 5; ++mf)
        #pragma unroll
        for (int r = 0; r < 4; ++r) {
            float v = acc[mf][r] + bias;
            v = v > 0.f ? v : 0.f;
            ob[(size_t)(mf * 16 + lk * 4 + r) * MID] = f2bf(v);
        }
}

// ---------------- conv2: implicit GEMM, LDS-staged A, fragment-packed B -------
__global__ __launch_bounds__(320) void conv2_mfma(
    const unsigned short* __restrict__ hdnp, const unsigned short* __restrict__ w2F,
    const float* __restrict__ b2, const float* __restrict__ scale_p,
    float* __restrict__ offs)
{
    const int by = blockIdx.x;
    const int b = by & 7, y = by >> 3;
    const int tid = threadIdx.x;
    const int nf = tid / 64;
    const int l = tid & 63, l15 = l & 15, lk = l >> 4;

    __shared__ __align__(16) unsigned short st[3 * 82 * STP];

    f32x4 acc[5];
    #pragma unroll
    for (int i = 0; i < 5; ++i) acc[i] = (f32x4){0.f, 0.f, 0.f, 0.f};

    const size_t rowbase = (size_t)b * PP + (size_t)y * PD;

    for (int e = tid; e < 3 * 82 * 8; e += 320) {
        int r   = e / 656;
        int rem = e - r * 656;
        int px  = rem >> 3;
        int c8  = rem & 7;
        const uint4 v = *(const uint4*)(hdnp + (rowbase + (size_t)r * PD + px) * MID + c8 * 8);
        *(uint4*)&st[(r * 82 + px) * STP + c8 * 8] = v;
    }
    __syncthreads();

    const unsigned short* bw = w2F + ((size_t)nf * 9 * 2 * 64) * 8;
    #pragma unroll
    for (int tap = 0; tap < 9; ++tap) {
        const int ky = tap / 3, kx = tap - ky * 3;
        #pragma unroll
        for (int cb = 0; cb < 2; ++cb) {
            bf16x8 bf = *(const bf16x8*)(bw + ((size_t)(tap * 2 + cb) * 64 + l) * 8);
            #pragma unroll
            for (int mf = 0; mf < 5; ++mf) {
                bf16x8 af = *(const bf16x8*)&st[(ky * 82 + mf * 16 + l15 + kx) * STP + cb * 32 + lk * 8];
                acc[mf] = __builtin_amdgcn_mfma_f32_16x16x32_bf16(af, bf, acc[mf], 0, 0, 0);
            }
        }
    }

    const int oc = nf * 16 + l15;
    if (oc < OFFC) {
        const float scale = scale_p[0];
        const float bias = b2[oc];
        float* ob = offs + ((size_t)b * OFFC + oc) * HW + y * WW;
        #pragma unroll
        for (int mf = 0; mf < 5; ++mf) {
            float4 v;
            v.x = (acc[mf][0] + bias) * scale;
            v.y = (acc[mf][1] + bias) * scale;
            v.z = (acc[mf][2] + bias) * scale;
            v.w = (acc[mf][3] + bias) * scale;
            *(float4*)(ob + mf * 16 + lk * 4) = v;
        }
    }
}

// ---------------- deformable conv 3x3: fp32 LDS window + pk-fma bilinear ------
// block = (b, y-pair, g): 640 thr = 10 waves = 2 rows x 5 x-tiles of 16 px.
// Stage padded rows r0..r0+5 converted to fp32, ch-plane-major LDS (63.1 KB).
__global__ __launch_bounds__(640) void deform_kernel(
    const unsigned short* __restrict__ rgbcp, const float* __restrict__ offs,
    const unsigned short* __restrict__ dwF, const float* __restrict__ db,
    float* __restrict__ out)
{
    const int b = blockIdx.x & 7;
    const int rem = blockIdx.x >> 3;      // 0..159 (y2 inner, g outer)
    const int y2 = rem % 40;
    const int g  = rem / 40;
    const int wv64 = threadIdx.x >> 6;    // 0..9
    const int h  = (wv64 >= 5) ? 1 : 0;   // row within pair
    const int wv = wv64 - h * 5;          // x-tile 0..4
    const int l = threadIdx.x & 63, l15 = l & 15, lk = l >> 4;

    const int y0 = y2 * 2;
    const int y  = y0 + h;
    const int x  = wv * 16 + l15;
    const int p  = y * WW + x;
    const int p0 = y * WW + wv * 16;
    const int r0 = min(max(y0 - 1, 0), PD - 6);    // staged padded rows r0..r0+5

    // fp32 window, ch-plane-major: plane q = lk*2+half (4 ch each), 492 pixels
    __shared__ __align__(16) float st[8 * QSTRIDE * 4];   // 63,104 B

    // ---- stage: 6 rows x 82 px x 32 ch, bf16 -> fp32 conversion ONCE ----
    const unsigned short* gsrc = rgbcp + ((size_t)b * PP + (size_t)r0 * PD) * C2 + g * CG;
    for (int e = threadIdx.x; e < 6 * 82 * 4; e += 640) {
        int pix = e >> 2;                 // 0..491 = r*82 + px
        int c8  = e & 3;
        int r   = pix / 82, px = pix - r * 82;
        uint4 v = *(const uint4*)(gsrc + ((size_t)r * PD + px) * C2 + c8 * 8);
        unsigned uu[4] = {v.x, v.y, v.z, v.w};
        float4 lo, hi;
        lo.x = __uint_as_float(uu[0] << 16); lo.y = __uint_as_float(uu[0] & 0xffff0000u);
        lo.z = __uint_as_float(uu[1] << 16); lo.w = __uint_as_float(uu[1] & 0xffff0000u);
        hi.x = __uint_as_float(uu[2] << 16); hi.y = __uint_as_float(uu[2] & 0xffff0000u);
        hi.z = __uint_as_float(uu[3] << 16); hi.w = __uint_as_float(uu[3] & 0xffff0000u);
        *(float4*)&st[((2 * c8)     * QSTRIDE + pix) * 4] = lo;
        *(float4*)&st[((2 * c8 + 1) * QSTRIDE + pix) * 4] = hi;
    }
    __syncthreads();

    // ---- offsets up front ----
    const float* ob = offs + ((size_t)b * OFFC + g * 18) * HW + p;
    float sy[9], sx[9];
    #pragma unroll
    for (int t = 0; t < 9; ++t) {
        float offy = ob[(size_t)(2 * t) * HW];
        float offx = ob[(size_t)(2 * t + 1) * HW];
        sy[t] = (float)(y + t / 3 - 1) + offy;
        sx[t] = (float)(x + t % 3 - 1) + offx;
    }

    f32x4 acc0 = (f32x4){0.f, 0.f, 0.f, 0.f};
    f32x4 acc1 = (f32x4){0.f, 0.f, 0.f, 0.f};
    const unsigned short* gb = rgbcp + (size_t)b * PP * C2 + g * CG + lk * 8;
    const unsigned short* wg = dwF + (size_t)g * 9 * 2 * 64 * 8 + (size_t)l * 8;
    const float* stlo = &st[(2 * lk) * QSTRIDE * 4];
    const float* sthi = &st[(2 * lk + 1) * QSTRIDE * 4];

    #pragma unroll
    for (int t = 0; t < 9; ++t) {
        float fy = floorf(sy[t]), fx = floorf(sx[t]);
        int iy = (int)fy, ix = (int)fx;
        float wy = sy[t] - fy, wx = sx[t] - fx;

        float my0 = ((unsigned)iy       < HH) ? 1.f : 0.f;
        float my1 = ((unsigned)(iy + 1) < HH) ? 1.f : 0.f;
        float mx0 = ((unsigned)ix       < WW) ? 1.f : 0.f;
        float mx1 = ((unsigned)(ix + 1) < WW) ? 1.f : 0.f;
        float w00 = (1.f - wy) * (1.f - wx) * my0 * mx0;
        float w01 = (1.f - wy) * wx         * my0 * mx1;
        float w10 = wy * (1.f - wx)         * my1 * mx0;
        float w11 = wy * wx                 * my1 * mx1;

        int cy0 = min(max(iy, 0), HH - 1) + 1;
        int cy1 = min(max(iy + 1, 0), HH - 1) + 1;
        int cx0 = min(max(ix, 0), WW - 1) + 1;
        int cx1 = min(max(ix + 1, 0), WW - 1) + 1;

        f32x4 smlo = (f32x4){0.f, 0.f, 0.f, 0.f};
        f32x4 smhi = (f32x4){0.f, 0.f, 0.f, 0.f};

        if (cy0 >= r0 && cy1 <= r0 + 5) {     // fast path: staged fp32 window
            const int i00 = ((cy0 - r0) * 82 + cx0) * 4;
            const int i01 = ((cy0 - r0) * 82 + cx1) * 4;
            const int i10 = ((cy1 - r0) * 82 + cx0) * 4;
            const int i11 = ((cy1 - r0) * 82 + cx1) * 4;
            f32x4 w00v = {w00, w00, w00, w00};
            f32x4 w01v = {w01, w01, w01, w01};
            f32x4 w10v = {w10, w10, w10, w10};
            f32x4 w11v = {w11, w11, w11, w11};
            smlo += *(const f32x4*)&stlo[i00] * w00v;
            smhi += *(const f32x4*)&sthi[i00] * w00v;
            smlo += *(const f32x4*)&stlo[i01] * w01v;
            smhi += *(const f32x4*)&sthi[i01] * w01v;
            smlo += *(const f32x4*)&stlo[i10] * w10v;
            smhi += *(const f32x4*)&sthi[i10] * w10v;
            smlo += *(const f32x4*)&stlo[i11] * w11v;
            smhi += *(const f32x4*)&sthi[i11] * w11v;
        } else {                               // rare: large offset -> global
            uint4 qq[4];
            qq[0] = *(const uint4*)(gb + ((size_t)cy0 * PD + cx0) * C2);
            qq[1] = *(const uint4*)(gb + ((size_t)cy0 * PD + cx1) * C2);
            qq[2] = *(const uint4*)(gb + ((size_t)cy1 * PD + cx0) * C2);
            qq[3] = *(const uint4*)(gb + ((size_t)cy1 * PD + cx1) * C2);
            float wq[4] = {w00, w01, w10, w11};
            #pragma unroll
            for (int c = 0; c < 4; ++c) {
                unsigned uu[4] = {qq[c].x, qq[c].y, qq[c].z, qq[c].w};
                f32x4 lo, hi;
                lo[0] = __uint_as_float(uu[0] << 16); lo[1] = __uint_as_float(uu[0] & 0xffff0000u);
                lo[2] = __uint_as_float(uu[1] << 16); lo[3] = __uint_as_float(uu[1] & 0xffff0000u);
                hi[0] = __uint_as_float(uu[2] << 16); hi[1] = __uint_as_float(uu[2] & 0xffff0000u);
                hi[2] = __uint_as_float(uu[3] << 16); hi[3] = __uint_as_float(uu[3] & 0xffff0000u);
                f32x4 wv4 = {wq[c], wq[c], wq[c], wq[c]};
                smlo += lo * wv4;
                smhi += hi * wv4;
            }
        }

        union { bf16x8 v; unsigned u[4]; } af;
        asm volatile("v_cvt_pk_bf16_f32 %0, %1, %2" : "=v"(af.u[0]) : "v"(smlo[0]), "v"(smlo[1]));
        asm volatile("v_cvt_pk_bf16_f32 %0, %1, %2" : "=v"(af.u[1]) : "v"(smlo[2]), "v"(smlo[3]));
        asm volatile("v_cvt_pk_bf16_f32 %0, %1, %2" : "=v"(af.u[2]) : "v"(smhi[0]), "v"(smhi[1]));
        asm volatile("v_cvt_pk_bf16_f32 %0, %1, %2" : "=v"(af.u[3]) : "v"(smhi[2]), "v"(smhi[3]));

        bf16x8 bf0 = *(const bf16x8*)(wg + (size_t)t * 2 * 64 * 8);
        bf16x8 bf1 = *(const bf16x8*)(wg + (size_t)t * 2 * 64 * 8 + 64 * 8);
        acc0 = __builtin_amdgcn_mfma_f32_16x16x32_bf16(af.v, bf0, acc0, 0, 0, 0);
        acc1 = __builtin_amdgcn_mfma_f32_16x16x32_bf16(af.v, bf1, acc1, 0, 0, 0);
    }

    {
        const int oc = g * CG + l15;
        const float bias = db[oc];
        float4 v;
        v.x = acc0[0] + bias; v.y = acc0[1] + bias;
        v.z = acc0[2] + bias; v.w = acc0[3] + bias;
        *(float4*)(out + ((size_t)b * CIN + oc) * HW + p0 + lk * 4) = v;
    }
    {
        const int oc = g * CG + 16 + l15;
        const float bias = db[oc];
        float4 v;
        v.x = acc1[0] + bias; v.y = acc1[1] + bias;
        v.z = acc1[2] + bias; v.w = acc1[3] + bias;
        *(float4*)(out + ((size_t)b * CIN + oc) * HW + p0 + lk * 4) = v;
    }
}

extern "C" void kernel_launch(void* const* d_in, const int* in_sizes, int n_in,
                              void* d_out, int out_size, void* d_ws, size_t ws_size,
                              hipStream_t stream) {
    const float* rgb     = (const float*)d_in[0];
    const float* thermal = (const float*)d_in[1];
    const float* w1      = (const float*)d_in[2];
    const float* b1      = (const float*)d_in[3];
    const float* w2      = (const float*)d_in[4];
    const float* b2      = (const float*)d_in[5];
    const float* dw      = (const float*)d_in[6];
    const float* db      = (const float*)d_in[7];
    const float* osc     = (const float*)d_in[8];

    char* w = (char*)d_ws;
    unsigned short* rgbcp = (unsigned short*)w;  w += (size_t)BB * PP * C2 * 2;
    unsigned short* hdnp  = (unsigned short*)w;  w += (size_t)BB * PP * MID * 2;
    float*          offs  = (float*)w;           w += (size_t)BB * OFFC * HW * 4;
    unsigned short* w1F   = (unsigned short*)w;  w += (size_t)147456 * 2;
    unsigned short* w2F   = (unsigned short*)w;  w += (size_t)46080 * 2;
    unsigned short* dwF   = (unsigned short*)w;  w += (size_t)36864 * 2;
    float* out = (float*)d_out;

    prep_kernel<<<dim3(1098), 512, 0, stream>>>(w1, w2, dw, rgb, thermal,
                                                w1F, w2F, dwF, rgbcp, hdnp);
    conv1_mfma<<<dim3(BB * HH), 256, 0, stream>>>(rgbcp, w1F, b1, hdnp);
    conv2_mfma<<<dim3(BB * HH), 320, 0, stream>>>(hdnp, w2F, b2, osc, offs);
    deform_kernel<<<dim3(BB * 40 * NG), 640, 0, stream>>>(rgbcp, offs, dwF, db, out);
}